// Round 1
// baseline (6337.732 us; speedup 1.0000x reference)
//
#include <hip/hip_runtime.h>
#include <math.h>

// Problem dims (fixed)
constexpr int Bn = 4, Tn = 1024, INDIM = 231, Dm = 512, Hn = 8, NCn = 1296;
constexpr int T2 = 512;          // after avgpool
constexpr int Mseq = Bn * Tn;    // 4096
constexpr int Mtc  = Bn * T2;    // 2048

enum { EPI_BIAS = 0, EPI_BIAS_RELU, EPI_BIAS_RES, EPI_BIAS_GELU, EPI_SS_GELU };

__device__ __forceinline__ float gelu_exact(float x) {
    return 0.5f * x * (1.0f + erff(x * 0.70710678118654752f));
}

// ---------------------------------------------------------------------------
// Generic 64x64 tile GEMM: C[M,N] = A[M,K] @ W[N,K]^T  (+ epilogue)
// KS>0 => A is a virtual im2col of channels-last [*, T2, 512] with kernel KS, pad PAD
// M must be a multiple of 64 (true for all uses). N,K arbitrary (guarded).
// ---------------------------------------------------------------------------
template<int EPI, int KS, int PAD>
__global__ __launch_bounds__(256)
void gemm64(const float* __restrict__ A, const float* __restrict__ W, float* __restrict__ C,
            int M, int N, int K,
            const float* __restrict__ bias, const float* __restrict__ resid,
            const float* __restrict__ scale, const float* __restrict__ shift)
{
    __shared__ float As[16][64];
    __shared__ float Bs[16][64];
    const int tid = threadIdx.x;
    const int bm = blockIdx.y * 64, bn = blockIdx.x * 64;
    const int ty = tid >> 4, tx = tid & 15;
    const int lm = tid >> 2;        // 0..63
    const int lk = (tid & 3) * 4;   // 0,4,8,12
    float acc[4][4] = {};
    const int nrow = bn + lm;
    const bool nok = nrow < N;

    for (int k0 = 0; k0 < K; k0 += 16) {
        float av[4], bv[4];
#pragma unroll
        for (int i = 0; i < 4; ++i) {
            const int kk = k0 + lk + i;
            if constexpr (KS > 0) {
                const int m = bm + lm;
                const int t = m & (T2 - 1);
                const int bi = m >> 9;
                const int ks = kk >> 9, c = kk & 511;
                const int tt = t + ks - PAD;
                av[i] = (tt >= 0 && tt < T2) ? A[((size_t)(bi * T2 + tt) << 9) + c] : 0.f;
            } else {
                av[i] = (kk < K) ? A[(size_t)(bm + lm) * K + kk] : 0.f;
            }
            bv[i] = (nok && kk < K) ? W[(size_t)nrow * K + kk] : 0.f;
        }
        __syncthreads();
#pragma unroll
        for (int i = 0; i < 4; ++i) { As[lk + i][lm] = av[i]; Bs[lk + i][lm] = bv[i]; }
        __syncthreads();
#pragma unroll
        for (int k = 0; k < 16; ++k) {
            const float4 a4 = *(const float4*)&As[k][ty * 4];
            const float4 b4 = *(const float4*)&Bs[k][tx * 4];
            const float aa[4] = {a4.x, a4.y, a4.z, a4.w};
            const float bb[4] = {b4.x, b4.y, b4.z, b4.w};
#pragma unroll
            for (int i = 0; i < 4; ++i)
#pragma unroll
                for (int j = 0; j < 4; ++j)
                    acc[i][j] = fmaf(aa[i], bb[j], acc[i][j]);
        }
    }

    const int cbase = bn + (tx << 2);
    if (cbase >= N) return;
    float bs[4] = {0.f, 0.f, 0.f, 0.f}, scv[4] = {}, shv[4] = {};
    if constexpr (EPI == EPI_SS_GELU) {
        const float4 s4 = *(const float4*)(scale + cbase);
        const float4 h4 = *(const float4*)(shift + cbase);
        scv[0] = s4.x; scv[1] = s4.y; scv[2] = s4.z; scv[3] = s4.w;
        shv[0] = h4.x; shv[1] = h4.y; shv[2] = h4.z; shv[3] = h4.w;
    } else {
        const float4 b4 = *(const float4*)(bias + cbase);
        bs[0] = b4.x; bs[1] = b4.y; bs[2] = b4.z; bs[3] = b4.w;
    }
#pragma unroll
    for (int i = 0; i < 4; ++i) {
        const int r = bm + (ty << 2) + i;
        float o[4];
#pragma unroll
        for (int j = 0; j < 4; ++j) o[j] = acc[i][j];
        if constexpr (EPI == EPI_SS_GELU) {
#pragma unroll
            for (int j = 0; j < 4; ++j) o[j] = gelu_exact(o[j] * scv[j] + shv[j]);
        } else {
#pragma unroll
            for (int j = 0; j < 4; ++j) o[j] += bs[j];
            if constexpr (EPI == EPI_BIAS_RELU) {
#pragma unroll
                for (int j = 0; j < 4; ++j) o[j] = fmaxf(o[j], 0.f);
            }
            if constexpr (EPI == EPI_BIAS_RES) {
                const float4 r4 = *(const float4*)(resid + (size_t)r * N + cbase);
                o[0] += r4.x; o[1] += r4.y; o[2] += r4.z; o[3] += r4.w;
            }
            if constexpr (EPI == EPI_BIAS_GELU) {
#pragma unroll
                for (int j = 0; j < 4; ++j) o[j] = gelu_exact(o[j]);
            }
        }
        *(float4*)(C + (size_t)r * N + cbase) = make_float4(o[0], o[1], o[2], o[3]);
    }
}

// ---------------------------------------------------------------------------
// 128x128 tile GEMM (8x8 per thread), for the wide GEMMs (QKV, FF1).
// M multiple of 128. Epilogue: bias or bias+relu.
// ---------------------------------------------------------------------------
template<int EPI>
__global__ __launch_bounds__(256)
void gemm128(const float* __restrict__ A, const float* __restrict__ W, float* __restrict__ C,
             int M, int N, int K, const float* __restrict__ bias)
{
    __shared__ float As[8][128];
    __shared__ float Bs[8][128];
    const int tid = threadIdx.x;
    const int bm = blockIdx.y * 128, bn = blockIdx.x * 128;
    const int ty = tid >> 4, tx = tid & 15;
    const int lm = tid >> 1;        // 0..127
    const int lk = (tid & 1) * 4;   // 0 or 4
    float acc[2][2][4][4] = {};
    const int nrow = bn + lm;
    const bool nok = nrow < N;

    for (int k0 = 0; k0 < K; k0 += 8) {
        float av[4], bv[4];
#pragma unroll
        for (int i = 0; i < 4; ++i) {
            const int kk = k0 + lk + i;
            av[i] = (kk < K) ? A[(size_t)(bm + lm) * K + kk] : 0.f;
            bv[i] = (nok && kk < K) ? W[(size_t)nrow * K + kk] : 0.f;
        }
        __syncthreads();
#pragma unroll
        for (int i = 0; i < 4; ++i) { As[lk + i][lm] = av[i]; Bs[lk + i][lm] = bv[i]; }
        __syncthreads();
#pragma unroll
        for (int k = 0; k < 8; ++k) {
            const float4 a0 = *(const float4*)&As[k][ty * 4];
            const float4 a1 = *(const float4*)&As[k][64 + ty * 4];
            const float4 b0 = *(const float4*)&Bs[k][tx * 4];
            const float4 b1 = *(const float4*)&Bs[k][64 + tx * 4];
            const float ar[2][4] = {{a0.x, a0.y, a0.z, a0.w}, {a1.x, a1.y, a1.z, a1.w}};
            const float br[2][4] = {{b0.x, b0.y, b0.z, b0.w}, {b1.x, b1.y, b1.z, b1.w}};
#pragma unroll
            for (int rh = 0; rh < 2; ++rh)
#pragma unroll
                for (int ch = 0; ch < 2; ++ch)
#pragma unroll
                    for (int i = 0; i < 4; ++i)
#pragma unroll
                        for (int j = 0; j < 4; ++j)
                            acc[rh][ch][i][j] = fmaf(ar[rh][i], br[ch][j], acc[rh][ch][i][j]);
        }
    }

#pragma unroll
    for (int ch = 0; ch < 2; ++ch) {
        const int cb = bn + ch * 64 + (tx << 2);
        if (cb >= N) continue;
        const float4 b4 = *(const float4*)(bias + cb);
        const float bs[4] = {b4.x, b4.y, b4.z, b4.w};
#pragma unroll
        for (int rh = 0; rh < 2; ++rh) {
#pragma unroll
            for (int i = 0; i < 4; ++i) {
                const int r = bm + rh * 64 + (ty << 2) + i;
                float o[4];
#pragma unroll
                for (int j = 0; j < 4; ++j) {
                    o[j] = acc[rh][ch][i][j] + bs[j];
                    if constexpr (EPI == EPI_BIAS_RELU) o[j] = fmaxf(o[j], 0.f);
                }
                *(float4*)(C + (size_t)r * N + cb) = make_float4(o[0], o[1], o[2], o[3]);
            }
        }
    }
}

// ---------------------------------------------------------------------------
// Flash attention: qkv [B*T, 3*512] packed (q|k|v), out [B*T, 512] (ctx, heads concat)
// grid (T/64, H, B), block 256. 64 queries/block, online softmax over 16 key tiles.
// ---------------------------------------------------------------------------
__global__ __launch_bounds__(256)
void attn_kernel(const float* __restrict__ qkv, float* __restrict__ out)
{
    const int b = blockIdx.z, h = blockIdx.y, q0 = blockIdx.x * 64;
    __shared__ float Qs[64][68];
    __shared__ float Kt[64][68];   // transposed: Kt[d][key]
    __shared__ float Vs[64][68];
    __shared__ float Ss[64][65];
    __shared__ float mrow[64], lrow[64], frow[64];
    const int tid = threadIdx.x;
    const int ty = tid >> 4, tx = tid & 15;

    {   // load Q tile (scaled)
        const int q = tid >> 2, d0 = (tid & 3) * 16;
        const float* src = qkv + ((size_t)(b * Tn + q0 + q)) * 1536 + h * 64 + d0;
#pragma unroll
        for (int i = 0; i < 4; ++i) {
            const float4 v = *(const float4*)(src + i * 4);
            Qs[q][d0 + i * 4 + 0] = v.x * 0.125f;
            Qs[q][d0 + i * 4 + 1] = v.y * 0.125f;
            Qs[q][d0 + i * 4 + 2] = v.z * 0.125f;
            Qs[q][d0 + i * 4 + 3] = v.w * 0.125f;
        }
    }
    if (tid < 64) { mrow[tid] = -1e30f; lrow[tid] = 0.f; }
    float ctx[4][4] = {};

    for (int kt = 0; kt < 16; ++kt) {
        __syncthreads();
        {   // load K (transposed) and V tiles
            const int key = tid >> 2, d0 = (tid & 3) * 16;
            const float* kp = qkv + ((size_t)(b * Tn + kt * 64 + key)) * 1536 + 512 + h * 64 + d0;
            const float* vp = kp + 512;
#pragma unroll
            for (int i = 0; i < 4; ++i) {
                const float4 kv = *(const float4*)(kp + i * 4);
                Kt[d0 + i * 4 + 0][key] = kv.x;
                Kt[d0 + i * 4 + 1][key] = kv.y;
                Kt[d0 + i * 4 + 2][key] = kv.z;
                Kt[d0 + i * 4 + 3][key] = kv.w;
                *(float4*)&Vs[key][d0 + i * 4] = *(const float4*)(vp + i * 4);
            }
        }
        __syncthreads();
        // phase 1: scores S = Q K^T (thread: 4q x 4k)
        float s[4][4] = {};
#pragma unroll
        for (int d0 = 0; d0 < 64; d0 += 4) {
            float qa[4][4];
#pragma unroll
            for (int qi = 0; qi < 4; ++qi) {
                const float4 q4 = *(const float4*)&Qs[ty * 4 + qi][d0];
                qa[qi][0] = q4.x; qa[qi][1] = q4.y; qa[qi][2] = q4.z; qa[qi][3] = q4.w;
            }
#pragma unroll
            for (int dd = 0; dd < 4; ++dd) {
                const float4 k4 = *(const float4*)&Kt[d0 + dd][tx * 4];
                const float kb[4] = {k4.x, k4.y, k4.z, k4.w};
#pragma unroll
                for (int qi = 0; qi < 4; ++qi)
#pragma unroll
                    for (int j = 0; j < 4; ++j)
                        s[qi][j] = fmaf(qa[qi][dd], kb[j], s[qi][j]);
            }
        }
#pragma unroll
        for (int qi = 0; qi < 4; ++qi)
#pragma unroll
            for (int j = 0; j < 4; ++j)
                Ss[ty * 4 + qi][tx * 4 + j] = s[qi][j];
        __syncthreads();
        // online softmax: 4 threads per row
        {
            const int r = tid >> 2, sub = tid & 3;
            float mt = -1e30f;
#pragma unroll
            for (int k = 0; k < 16; ++k) mt = fmaxf(mt, Ss[r][sub * 16 + k]);
            mt = fmaxf(mt, __shfl_xor(mt, 1));
            mt = fmaxf(mt, __shfl_xor(mt, 2));
            const float mold = mrow[r];
            const float mnew = fmaxf(mold, mt);
            float sum = 0.f;
#pragma unroll
            for (int k = 0; k < 16; ++k) {
                const float p = __expf(Ss[r][sub * 16 + k] - mnew);
                Ss[r][sub * 16 + k] = p;
                sum += p;
            }
            sum += __shfl_xor(sum, 1);
            sum += __shfl_xor(sum, 2);
            if (sub == 0) {
                const float f = __expf(mold - mnew);
                frow[r] = f;
                lrow[r] = lrow[r] * f + sum;
                mrow[r] = mnew;
            }
        }
        __syncthreads();
        // phase 2: ctx = ctx*f + P V
        float fq[4];
#pragma unroll
        for (int qi = 0; qi < 4; ++qi) fq[qi] = frow[ty * 4 + qi];
#pragma unroll
        for (int qi = 0; qi < 4; ++qi)
#pragma unroll
            for (int j = 0; j < 4; ++j) ctx[qi][j] *= fq[qi];
        for (int k = 0; k < 64; ++k) {
            const float4 v4 = *(const float4*)&Vs[k][tx * 4];
            const float vb[4] = {v4.x, v4.y, v4.z, v4.w};
#pragma unroll
            for (int qi = 0; qi < 4; ++qi) {
                const float p = Ss[ty * 4 + qi][k];
#pragma unroll
                for (int j = 0; j < 4; ++j) ctx[qi][j] = fmaf(p, vb[j], ctx[qi][j]);
            }
        }
    }
#pragma unroll
    for (int qi = 0; qi < 4; ++qi) {
        const float inv = 1.f / lrow[ty * 4 + qi];
        float4 o = make_float4(ctx[qi][0] * inv, ctx[qi][1] * inv, ctx[qi][2] * inv, ctx[qi][3] * inv);
        *(float4*)&out[((size_t)(b * Tn + q0 + ty * 4 + qi)) * 512 + h * 64 + tx * 4] = o;
    }
}

// ---------------------------------------------------------------------------
// LayerNorm over rows of 512; one wave per row; optional fused sinusoidal PE.
// ---------------------------------------------------------------------------
__device__ __forceinline__ float pe_val(int t, int d) {
    const int k = d & ~1;
    const float invf = __expf(-(float)k * (9.210340371976184f / 512.f)); // 10000^(-k/512)
    const float ang = (float)t * invf;
    return (d & 1) ? cosf(ang) : sinf(ang);
}

__global__ __launch_bounds__(256)
void ln_kernel(const float* __restrict__ in, float* __restrict__ out,
               const float* __restrict__ g, const float* __restrict__ bsh, int addpe)
{
    const int lane = threadIdx.x & 63;
    const int row = blockIdx.x * 4 + (threadIdx.x >> 6);
    const float* src = in + (size_t)row * Dm;
    const int c0 = lane * 4;
    const float4 v0 = *(const float4*)(src + c0);
    const float4 v1 = *(const float4*)(src + 256 + c0);
    float s  = v0.x + v0.y + v0.z + v0.w + v1.x + v1.y + v1.z + v1.w;
    float ss = v0.x * v0.x + v0.y * v0.y + v0.z * v0.z + v0.w * v0.w
             + v1.x * v1.x + v1.y * v1.y + v1.z * v1.z + v1.w * v1.w;
#pragma unroll
    for (int off = 32; off; off >>= 1) { s += __shfl_xor(s, off); ss += __shfl_xor(ss, off); }
    const float mean = s * (1.f / 512.f);
    const float var = ss * (1.f / 512.f) - mean * mean;
    const float rstd = rsqrtf(var + 1e-5f);
    const float4 g0 = *(const float4*)(g + c0),   g1 = *(const float4*)(g + 256 + c0);
    const float4 b0 = *(const float4*)(bsh + c0), b1 = *(const float4*)(bsh + 256 + c0);
    float o0[4] = {(v0.x - mean) * rstd * g0.x + b0.x, (v0.y - mean) * rstd * g0.y + b0.y,
                   (v0.z - mean) * rstd * g0.z + b0.z, (v0.w - mean) * rstd * g0.w + b0.w};
    float o1[4] = {(v1.x - mean) * rstd * g1.x + b1.x, (v1.y - mean) * rstd * g1.y + b1.y,
                   (v1.z - mean) * rstd * g1.z + b1.z, (v1.w - mean) * rstd * g1.w + b1.w};
    if (addpe) {
        const int t = row & (Tn - 1);
#pragma unroll
        for (int j = 0; j < 4; ++j) { o0[j] += pe_val(t, c0 + j); o1[j] += pe_val(t, 256 + c0 + j); }
    }
    *(float4*)(out + (size_t)row * Dm + c0) = make_float4(o0[0], o0[1], o0[2], o0[3]);
    *(float4*)(out + (size_t)row * Dm + 256 + c0) = make_float4(o1[0], o1[1], o1[2], o1[3]);
}

// ---------------------------------------------------------------------------
// small elementwise helpers
// ---------------------------------------------------------------------------
__global__ void copy_k(const float* __restrict__ a, float* __restrict__ o, int n4) {
    const int i = blockIdx.x * blockDim.x + threadIdx.x;
    if (i < n4) ((float4*)o)[i] = ((const float4*)a)[i];
}
__global__ void add_k(float* __restrict__ o, const float* __restrict__ a, int n4) {
    const int i = blockIdx.x * blockDim.x + threadIdx.x;
    if (i < n4) {
        float4 x = ((float4*)o)[i];
        const float4 y = ((const float4*)a)[i];
        x.x += y.x; x.y += y.y; x.z += y.z; x.w += y.w;
        ((float4*)o)[i] = x;
    }
}
__global__ void pool_k(const float* __restrict__ x, float* __restrict__ o) {
    const int i = blockIdx.x * blockDim.x + threadIdx.x;  // over 262144 float4s
    if (i < (Mtc * Dm) / 4) {
        const int flat = i * 4;
        const int row = flat >> 9, col = flat & 511;
        const int b = row >> 9, t2 = row & 511;
        const float* p0 = x + ((size_t)(b * Tn + 2 * t2) << 9) + col;
        const float4 u = *(const float4*)p0;
        const float4 w = *(const float4*)(p0 + 512);
        *(float4*)(o + flat) = make_float4(0.5f * (u.x + w.x), 0.5f * (u.y + w.y),
                                           0.5f * (u.z + w.z), 0.5f * (u.w + w.w));
    }
}
__global__ void wtrans_k(const float* __restrict__ w, float* __restrict__ wt, int O, int Cc, int KS) {
    const int i = blockIdx.x * blockDim.x + threadIdx.x;
    const int n = O * Cc * KS;
    if (i < n) {
        const int o = i / (Cc * KS);
        const int rem = i - o * (Cc * KS);
        const int c = rem / KS, ks = rem - c * KS;
        wt[((size_t)o * KS + ks) * Cc + c] = w[i];
    }
}
__global__ void bnfold_k(const float* __restrict__ g, const float* __restrict__ b,
                         const float* __restrict__ m, const float* __restrict__ v,
                         const float* __restrict__ cb, float* __restrict__ sc, float* __restrict__ sh) {
    const int i = blockIdx.x * blockDim.x + threadIdx.x;
    if (i < Dm) {
        const float s = g[i] * rsqrtf(v[i] + 1e-5f);
        sc[i] = s;
        sh[i] = (cb[i] - m[i]) * s + b[i];
    }
}

// ---------------------------------------------------------------------------
extern "C" void kernel_launch(void* const* d_in, const int* in_sizes, int n_in,
                              void* d_out, int out_size, void* d_ws, size_t ws_size,
                              hipStream_t stream)
{
    (void)in_sizes; (void)n_in; (void)out_size; (void)ws_size;
    const float* poses   = (const float*)d_in[0];
    const float* embed_w = (const float*)d_in[1];
    const float* embed_b = (const float*)d_in[2];
    const float* ln0_g   = (const float*)d_in[3];
    const float* ln0_b   = (const float*)d_in[4];
    const float* inw  = (const float*)d_in[5];
    const float* inb  = (const float*)d_in[6];
    const float* outw = (const float*)d_in[7];
    const float* outb = (const float*)d_in[8];
    const float* ln1g = (const float*)d_in[9];
    const float* ln1b = (const float*)d_in[10];
    const float* ln2g = (const float*)d_in[11];
    const float* ln2b = (const float*)d_in[12];
    const float* ff1w = (const float*)d_in[13];
    const float* ff1b = (const float*)d_in[14];
    const float* ff2w = (const float*)d_in[15];
    const float* ff2b = (const float*)d_in[16];
    const float* conv1w = (const float*)d_in[17];
    const float* conv1b = (const float*)d_in[18];
    const float* bn1g = (const float*)d_in[19];
    const float* bn1b = (const float*)d_in[20];
    const float* bn1m = (const float*)d_in[21];
    const float* bn1v = (const float*)d_in[22];
    const float* conv2w = (const float*)d_in[23];
    const float* conv2b = (const float*)d_in[24];
    const float* bn2g = (const float*)d_in[25];
    const float* bn2b = (const float*)d_in[26];
    const float* bn2m = (const float*)d_in[27];
    const float* bn2v = (const float*)d_in[28];
    const float* fc1w = (const float*)d_in[29];
    const float* fc1b = (const float*)d_in[30];
    const float* fc2w = (const float*)d_in[31];
    const float* fc2b = (const float*)d_in[32];

    float* x    = (float*)d_ws;            // 2M floats
    float* hb   = x + (1 << 21);           // 2M floats
    float* big  = hb + (1 << 21);          // 8M floats (qkv / ff1 / tail scratch)
    float* resb = big + (1 << 23);         // 2M floats
    float* outp = (float*)d_out;

    // head: embed GEMM + LN + positional encoding
    gemm64<EPI_BIAS, 0, 0><<<dim3(8, 64), 256, 0, stream>>>(
        poses, embed_w, hb, Mseq, 512, INDIM, embed_b, nullptr, nullptr, nullptr);
    ln_kernel<<<1024, 256, 0, stream>>>(hb, x, ln0_g, ln0_b, 1);

    for (int i = 0; i < 8; ++i) {
        if (i == 2 || i == 4 || i == 6)
            copy_k<<<2048, 256, 0, stream>>>(x, resb, 1 << 19);
        ln_kernel<<<1024, 256, 0, stream>>>(x, hb, ln1g + i * 512, ln1b + i * 512, 0);
        gemm128<EPI_BIAS><<<dim3(12, 32), 256, 0, stream>>>(
            hb, inw + (size_t)i * 1536 * 512, big, Mseq, 1536, 512, inb + i * 1536);
        attn_kernel<<<dim3(16, 8, 4), 256, 0, stream>>>(big, hb);
        gemm64<EPI_BIAS_RES, 0, 0><<<dim3(8, 64), 256, 0, stream>>>(
            hb, outw + (size_t)i * 512 * 512, x, Mseq, 512, 512, outb + i * 512, x, nullptr, nullptr);
        ln_kernel<<<1024, 256, 0, stream>>>(x, hb, ln2g + i * 512, ln2b + i * 512, 0);
        gemm128<EPI_BIAS_RELU><<<dim3(16, 32), 256, 0, stream>>>(
            hb, ff1w + (size_t)i * 2048 * 512, big, Mseq, 2048, 512, ff1b + i * 2048);
        gemm64<EPI_BIAS_RES, 0, 0><<<dim3(8, 64), 256, 0, stream>>>(
            big, ff2w + (size_t)i * 512 * 2048, x, Mseq, 512, 2048, ff2b + i * 512, x, nullptr, nullptr);
        if (i == 3 || i == 5 || i == 7)
            add_k<<<2048, 256, 0, stream>>>(x, resb, 1 << 19);
    }

    // tail (channels-last): pool -> conv1(BN,GELU) -> conv2(BN,GELU) -> fc1(GELU) -> fc2
    float* pool = big;                       // 1M floats
    float* c1o  = big + (1 << 20);           // 1M
    float* c2o  = big + (2 << 20);           // 1M
    float* f1o  = big + (3 << 20);           // 0.5M
    float* w1t  = big + 3670016;             // 512*5*512 = 1310720
    float* w2t  = big + 5242880;             // 512*3*512 = 786432
    float* sc1  = big + 6291456;
    float* sh1  = sc1 + 512;
    float* sc2  = sh1 + 512;
    float* sh2  = sc2 + 512;

    pool_k<<<1024, 256, 0, stream>>>(x, pool);
    wtrans_k<<<(512 * 512 * 5 + 255) / 256, 256, 0, stream>>>(conv1w, w1t, 512, 512, 5);
    bnfold_k<<<2, 256, 0, stream>>>(bn1g, bn1b, bn1m, bn1v, conv1b, sc1, sh1);
    gemm64<EPI_SS_GELU, 5, 2><<<dim3(8, 32), 256, 0, stream>>>(
        pool, w1t, c1o, Mtc, 512, 2560, nullptr, nullptr, sc1, sh1);
    wtrans_k<<<(512 * 512 * 3 + 255) / 256, 256, 0, stream>>>(conv2w, w2t, 512, 512, 3);
    bnfold_k<<<2, 256, 0, stream>>>(bn2g, bn2b, bn2m, bn2v, conv2b, sc2, sh2);
    gemm64<EPI_SS_GELU, 3, 1><<<dim3(8, 32), 256, 0, stream>>>(
        c1o, w2t, c2o, Mtc, 512, 1536, nullptr, nullptr, sc2, sh2);
    gemm64<EPI_BIAS_GELU, 0, 0><<<dim3(4, 32), 256, 0, stream>>>(
        c2o, fc1w, f1o, Mtc, 256, 512, fc1b, nullptr, nullptr, nullptr);
    gemm64<EPI_BIAS, 0, 0><<<dim3(21, 32), 256, 0, stream>>>(
        f1o, fc2w, outp, Mtc, NCn, 256, fc2b, nullptr, nullptr, nullptr);
}

// Round 2
// 2446.470 us; speedup vs baseline: 2.5906x; 2.5906x over previous
//
#include <hip/hip_runtime.h>
#include <math.h>

using u16 = unsigned short;
typedef __attribute__((ext_vector_type(8))) __bf16 bf16x8;
typedef __attribute__((ext_vector_type(4))) float f32x4;

constexpr int Bn = 4, Tn = 1024, INDIM = 231, Dm = 512, NCn = 1296;
constexpr int T2 = 512;
constexpr int Mseq = Bn * Tn;    // 4096
constexpr int Mtc  = Bn * T2;    // 2048

enum { EPI_BIAS = 0, EPI_BIAS_RELU, EPI_BIAS_RES, EPI_BIAS_GELU, EPI_SS_GELU };

__device__ __forceinline__ float gelu_exact(float x) {
    return 0.5f * x * (1.0f + erff(x * 0.70710678118654752f));
}
__device__ __forceinline__ u16 f2b(float f) {
    unsigned u = __builtin_bit_cast(unsigned, f);
    return (u16)((u + 0x7FFFu + ((u >> 16) & 1u)) >> 16);
}
__device__ __forceinline__ unsigned pack2(float a, float b) {
    return (unsigned)f2b(a) | ((unsigned)f2b(b) << 16);
}

typedef __attribute__((address_space(3))) void lds_void;
typedef __attribute__((address_space(1))) void g_void;
__device__ __forceinline__ void gld16(const void* g, void* l) {
    __builtin_amdgcn_global_load_lds((g_void*)(uintptr_t)g, (lds_void*)(uintptr_t)l, 16, 0, 0);
}

// ---------------------------------------------------------------------------
// bf16 MFMA GEMM, m97 structure: 128x128 tile, 4 waves, BK=32, 16x16x32 MFMA.
// C[M,N] = A[M,K](bf16, row stride lda) @ W[N,K](bf16)^T  + epilogue.
// IPAD/OPAD: conv im2col row remapping on padded channels-last buffers.
// M mult of 128, K mult of 32; N tail guarded (W rows clamped, stores guarded).
// ---------------------------------------------------------------------------
template<int EPI, bool OB, int IPAD, int OPAD>
__global__ __launch_bounds__(256)
void gemm_bf(const u16* __restrict__ A, int lda,
             const u16* __restrict__ W,
             float* __restrict__ Cf, u16* __restrict__ Cb,
             int M, int N, int K,
             const float* __restrict__ bias, const float* __restrict__ resid,
             const float* __restrict__ scale, const float* __restrict__ shift)
{
    __shared__ __align__(16) u16 As[128 * 32];
    __shared__ __align__(16) u16 Bs[128 * 32];
    const int tid = threadIdx.x;
    const int bm = blockIdx.y * 128, bn = blockIdx.x * 128;
    const int w = tid >> 6, lane = tid & 63;
    const int wr = (w >> 1) * 64, wc = (w & 1) * 64;
    const int lr = lane & 15, lhi = lane >> 4;
    const int lkb = lhi * 8;

    // staging: thread t loads 16B: row t>>2 (+64), k-chunk (t&3)*8
    const int sr = tid >> 2, sk = (tid & 3) * 8;
    const int r0 = bm + sr, r1 = r0 + 64;
    const u16* ap0 = A + (size_t)(r0 + 2 * IPAD * (r0 >> 9)) * lda + sk;
    const u16* ap1 = A + (size_t)(r1 + 2 * IPAD * (r1 >> 9)) * lda + sk;
    int wr0 = bn + sr;      if (wr0 >= N) wr0 = N - 1;
    int wr1 = bn + 64 + sr; if (wr1 >= N) wr1 = N - 1;
    const u16* wp0 = W + (size_t)wr0 * K + sk;
    const u16* wp1 = W + (size_t)wr1 * K + sk;
    u16* la0 = &As[tid * 8];
    u16* la1 = &As[2048 + tid * 8];
    u16* lb0 = &Bs[tid * 8];
    u16* lb1 = &Bs[2048 + tid * 8];

    f32x4 acc[4][4] = {};
    const u16* arp = &As[(wr + lr) * 32 + lkb];
    const u16* brp = &Bs[(wc + lr) * 32 + lkb];

    for (int k0 = 0; k0 < K; k0 += 32) {
        gld16(ap0 + k0, la0);
        gld16(ap1 + k0, la1);
        gld16(wp0 + k0, lb0);
        gld16(wp1 + k0, lb1);
        __syncthreads();
        bf16x8 af[4], bf[4];
#pragma unroll
        for (int m = 0; m < 4; ++m) af[m] = *(const bf16x8*)(arp + m * 512);
#pragma unroll
        for (int n = 0; n < 4; ++n) bf[n] = *(const bf16x8*)(brp + n * 512);
#pragma unroll
        for (int m = 0; m < 4; ++m)
#pragma unroll
            for (int n = 0; n < 4; ++n)
                acc[m][n] = __builtin_amdgcn_mfma_f32_16x16x32_bf16(af[m], bf[n], acc[m][n], 0, 0, 0);
        __syncthreads();
    }

    // epilogue: C/D layout col=lane&15, row=(lane>>4)*4+reg
    const int col0 = bn + wc + lr;
    const int row0 = bm + wr + lhi * 4;
#pragma unroll
    for (int n = 0; n < 4; ++n) {
        const int col = col0 + n * 16;
        if (col >= N) continue;
        float bv = 0.f, sv = 0.f, hv = 0.f;
        if constexpr (EPI == EPI_SS_GELU) { sv = scale[col]; hv = shift[col]; }
        else bv = bias[col];
#pragma unroll
        for (int m = 0; m < 4; ++m) {
#pragma unroll
            for (int j = 0; j < 4; ++j) {
                const int r = row0 + m * 16 + j;
                const int orow = r + OPAD * (2 * (r >> 9) + 1);
                float o = acc[m][n][j];
                if constexpr (EPI == EPI_SS_GELU) {
                    o = gelu_exact(o * sv + hv);
                } else {
                    o += bv;
                    if constexpr (EPI == EPI_BIAS_RELU) o = fmaxf(o, 0.f);
                    if constexpr (EPI == EPI_BIAS_GELU) o = gelu_exact(o);
                    if constexpr (EPI == EPI_BIAS_RES) o += resid[(size_t)r * N + col];
                }
                if constexpr (OB) Cb[(size_t)orow * N + col] = f2b(o);
                else              Cf[(size_t)orow * N + col] = o;
            }
        }
    }
}

// ---------------------------------------------------------------------------
// Flash attention (fp32 math): qkv [B*T,1536] fp32 packed, out bf16 [B*T,512]
// ---------------------------------------------------------------------------
__global__ __launch_bounds__(256)
void attn_kernel(const float* __restrict__ qkv, u16* __restrict__ out)
{
    const int b = blockIdx.z, h = blockIdx.y, q0 = blockIdx.x * 64;
    __shared__ float Qs[64][68];
    __shared__ float Kt[64][68];
    __shared__ float Vs[64][68];
    __shared__ float Ss[64][65];
    __shared__ float mrow[64], lrow[64], frow[64];
    const int tid = threadIdx.x;
    const int ty = tid >> 4, tx = tid & 15;

    {
        const int q = tid >> 2, d0 = (tid & 3) * 16;
        const float* src = qkv + ((size_t)(b * Tn + q0 + q)) * 1536 + h * 64 + d0;
#pragma unroll
        for (int i = 0; i < 4; ++i) {
            const float4 v = *(const float4*)(src + i * 4);
            Qs[q][d0 + i * 4 + 0] = v.x * 0.125f;
            Qs[q][d0 + i * 4 + 1] = v.y * 0.125f;
            Qs[q][d0 + i * 4 + 2] = v.z * 0.125f;
            Qs[q][d0 + i * 4 + 3] = v.w * 0.125f;
        }
    }
    if (tid < 64) { mrow[tid] = -1e30f; lrow[tid] = 0.f; }
    float ctx[4][4] = {};

    for (int kt = 0; kt < 16; ++kt) {
        __syncthreads();
        {
            const int key = tid >> 2, d0 = (tid & 3) * 16;
            const float* kp = qkv + ((size_t)(b * Tn + kt * 64 + key)) * 1536 + 512 + h * 64 + d0;
            const float* vp = kp + 512;
#pragma unroll
            for (int i = 0; i < 4; ++i) {
                const float4 kv = *(const float4*)(kp + i * 4);
                Kt[d0 + i * 4 + 0][key] = kv.x;
                Kt[d0 + i * 4 + 1][key] = kv.y;
                Kt[d0 + i * 4 + 2][key] = kv.z;
                Kt[d0 + i * 4 + 3][key] = kv.w;
                *(float4*)&Vs[key][d0 + i * 4] = *(const float4*)(vp + i * 4);
            }
        }
        __syncthreads();
        float s[4][4] = {};
#pragma unroll
        for (int d0 = 0; d0 < 64; d0 += 4) {
            float qa[4][4];
#pragma unroll
            for (int qi = 0; qi < 4; ++qi) {
                const float4 q4 = *(const float4*)&Qs[ty * 4 + qi][d0];
                qa[qi][0] = q4.x; qa[qi][1] = q4.y; qa[qi][2] = q4.z; qa[qi][3] = q4.w;
            }
#pragma unroll
            for (int dd = 0; dd < 4; ++dd) {
                const float4 k4 = *(const float4*)&Kt[d0 + dd][tx * 4];
                const float kb[4] = {k4.x, k4.y, k4.z, k4.w};
#pragma unroll
                for (int qi = 0; qi < 4; ++qi)
#pragma unroll
                    for (int j = 0; j < 4; ++j)
                        s[qi][j] = fmaf(qa[qi][dd], kb[j], s[qi][j]);
            }
        }
#pragma unroll
        for (int qi = 0; qi < 4; ++qi)
#pragma unroll
            for (int j = 0; j < 4; ++j)
                Ss[ty * 4 + qi][tx * 4 + j] = s[qi][j];
        __syncthreads();
        {
            const int r = tid >> 2, sub = tid & 3;
            float mt = -1e30f;
#pragma unroll
            for (int k = 0; k < 16; ++k) mt = fmaxf(mt, Ss[r][sub * 16 + k]);
            mt = fmaxf(mt, __shfl_xor(mt, 1));
            mt = fmaxf(mt, __shfl_xor(mt, 2));
            const float mold = mrow[r];
            const float mnew = fmaxf(mold, mt);
            float sum = 0.f;
#pragma unroll
            for (int k = 0; k < 16; ++k) {
                const float p = __expf(Ss[r][sub * 16 + k] - mnew);
                Ss[r][sub * 16 + k] = p;
                sum += p;
            }
            sum += __shfl_xor(sum, 1);
            sum += __shfl_xor(sum, 2);
            if (sub == 0) {
                const float f = __expf(mold - mnew);
                frow[r] = f;
                lrow[r] = lrow[r] * f + sum;
                mrow[r] = mnew;
            }
        }
        __syncthreads();
        float fq[4];
#pragma unroll
        for (int qi = 0; qi < 4; ++qi) fq[qi] = frow[ty * 4 + qi];
#pragma unroll
        for (int qi = 0; qi < 4; ++qi)
#pragma unroll
            for (int j = 0; j < 4; ++j) ctx[qi][j] *= fq[qi];
        for (int k = 0; k < 64; ++k) {
            const float4 v4 = *(const float4*)&Vs[k][tx * 4];
            const float vb[4] = {v4.x, v4.y, v4.z, v4.w};
#pragma unroll
            for (int qi = 0; qi < 4; ++qi) {
                const float p = Ss[ty * 4 + qi][k];
#pragma unroll
                for (int j = 0; j < 4; ++j) ctx[qi][j] = fmaf(p, vb[j], ctx[qi][j]);
            }
        }
    }
#pragma unroll
    for (int qi = 0; qi < 4; ++qi) {
        const float inv = 1.f / lrow[ty * 4 + qi];
        ushort4 o4 = make_ushort4(f2b(ctx[qi][0] * inv), f2b(ctx[qi][1] * inv),
                                  f2b(ctx[qi][2] * inv), f2b(ctx[qi][3] * inv));
        *(ushort4*)&out[((size_t)(b * Tn + q0 + ty * 4 + qi)) * 512 + h * 64 + tx * 4] = o4;
    }
}

// ---------------------------------------------------------------------------
// LayerNorm, one wave per row; PE variant writes fp32, layer variant writes bf16
// ---------------------------------------------------------------------------
__device__ __forceinline__ float pe_val(int t, int d) {
    const int k = d & ~1;
    const float invf = __expf(-(float)k * (9.210340371976184f / 512.f));
    const float ang = (float)t * invf;
    return (d & 1) ? cosf(ang) : sinf(ang);
}

template<bool OB, bool PE>
__global__ __launch_bounds__(256)
void ln_k(const float* __restrict__ in, float* __restrict__ outf, u16* __restrict__ outb,
          const float* __restrict__ g, const float* __restrict__ bsh)
{
    const int lane = threadIdx.x & 63;
    const int row = blockIdx.x * 4 + (threadIdx.x >> 6);
    const float* src = in + (size_t)row * Dm;
    const int c0 = lane * 4;
    const float4 v0 = *(const float4*)(src + c0);
    const float4 v1 = *(const float4*)(src + 256 + c0);
    float s  = v0.x + v0.y + v0.z + v0.w + v1.x + v1.y + v1.z + v1.w;
    float ss = v0.x * v0.x + v0.y * v0.y + v0.z * v0.z + v0.w * v0.w
             + v1.x * v1.x + v1.y * v1.y + v1.z * v1.z + v1.w * v1.w;
#pragma unroll
    for (int off = 32; off; off >>= 1) { s += __shfl_xor(s, off); ss += __shfl_xor(ss, off); }
    const float mean = s * (1.f / 512.f);
    const float var = ss * (1.f / 512.f) - mean * mean;
    const float rstd = rsqrtf(var + 1e-5f);
    const float4 g0 = *(const float4*)(g + c0),   g1 = *(const float4*)(g + 256 + c0);
    const float4 b0 = *(const float4*)(bsh + c0), b1 = *(const float4*)(bsh + 256 + c0);
    float o0[4] = {(v0.x - mean) * rstd * g0.x + b0.x, (v0.y - mean) * rstd * g0.y + b0.y,
                   (v0.z - mean) * rstd * g0.z + b0.z, (v0.w - mean) * rstd * g0.w + b0.w};
    float o1[4] = {(v1.x - mean) * rstd * g1.x + b1.x, (v1.y - mean) * rstd * g1.y + b1.y,
                   (v1.z - mean) * rstd * g1.z + b1.z, (v1.w - mean) * rstd * g1.w + b1.w};
    if constexpr (PE) {
        const int t = row & (Tn - 1);
#pragma unroll
        for (int j = 0; j < 4; ++j) { o0[j] += pe_val(t, c0 + j); o1[j] += pe_val(t, 256 + c0 + j); }
    }
    if constexpr (OB) {
        *(ushort4*)(outb + (size_t)row * Dm + c0) =
            make_ushort4(f2b(o0[0]), f2b(o0[1]), f2b(o0[2]), f2b(o0[3]));
        *(ushort4*)(outb + (size_t)row * Dm + 256 + c0) =
            make_ushort4(f2b(o1[0]), f2b(o1[1]), f2b(o1[2]), f2b(o1[3]));
    } else {
        *(float4*)(outf + (size_t)row * Dm + c0) = make_float4(o0[0], o0[1], o0[2], o0[3]);
        *(float4*)(outf + (size_t)row * Dm + 256 + c0) = make_float4(o1[0], o1[1], o1[2], o1[3]);
    }
}

// ---------------------------------------------------------------------------
// helpers
// ---------------------------------------------------------------------------
__global__ void copy_k(const float* __restrict__ a, float* __restrict__ o, int n4) {
    const int i = blockIdx.x * blockDim.x + threadIdx.x;
    if (i < n4) ((float4*)o)[i] = ((const float4*)a)[i];
}
__global__ void add_k(float* __restrict__ o, const float* __restrict__ a, int n4) {
    const int i = blockIdx.x * blockDim.x + threadIdx.x;
    if (i < n4) {
        float4 x = ((float4*)o)[i];
        const float4 y = ((const float4*)a)[i];
        x.x += y.x; x.y += y.y; x.z += y.z; x.w += y.w;
        ((float4*)o)[i] = x;
    }
}
// per-layer weight convert: {qkv 786432, out 262144, ff1 1048576, ff2 1048576}
__global__ void cvt_layer_k(const float* __restrict__ inw, const float* __restrict__ outw,
                            const float* __restrict__ ff1w, const float* __restrict__ ff2w,
                            int layer, u16* __restrict__ dst) {
    const int i = (blockIdx.x * 256 + threadIdx.x) * 8;
    const float* src;
    if (i < 786432)       src = inw  + (size_t)layer *  786432 + i;
    else if (i < 1048576) src = outw + (size_t)layer *  262144 + (i - 786432);
    else if (i < 2097152) src = ff1w + (size_t)layer * 1048576 + (i - 1048576);
    else                  src = ff2w + (size_t)layer * 1048576 + (i - 2097152);
    const float4 a = *(const float4*)src, b = *(const float4*)(src + 4);
    uint4 o; o.x = pack2(a.x, a.y); o.y = pack2(a.z, a.w); o.z = pack2(b.x, b.y); o.w = pack2(b.z, b.w);
    *(uint4*)(dst + i) = o;
}
__global__ void cvt8_k(const float* __restrict__ in, u16* __restrict__ out, int n8) {
    const int t = blockIdx.x * 256 + threadIdx.x;
    if (t >= n8) return;
    const int i = t * 8;
    const float4 a = *(const float4*)(in + i), b = *(const float4*)(in + i + 4);
    uint4 o; o.x = pack2(a.x, a.y); o.y = pack2(a.z, a.w); o.z = pack2(b.x, b.y); o.w = pack2(b.z, b.w);
    *(uint4*)(out + i) = o;
}
__global__ void padposes_k(const float* __restrict__ p, u16* __restrict__ o, int rows) {
    const int i = blockIdx.x * 256 + threadIdx.x;
    if (i >= rows * 256) return;
    const int r = i >> 8, c = i & 255;
    o[i] = (c < INDIM) ? f2b(p[r * INDIM + c]) : (u16)0;
}
__global__ void zero_k(uint4* __restrict__ p, int n16) {
    const int i = blockIdx.x * 256 + threadIdx.x;
    if (i < n16) p[i] = make_uint4(0, 0, 0, 0);
}
__global__ void pool_k(const float* __restrict__ x, u16* __restrict__ o) {
    const int i = blockIdx.x * 256 + threadIdx.x;
    if (i >= 262144) return;
    const int flat = i * 4;
    const int row = flat >> 9, col = flat & 511;
    const int b = row >> 9, t2 = row & 511;
    const float* p0 = x + ((size_t)(b * Tn + 2 * t2) << 9) + col;
    const float4 u = *(const float4*)p0;
    const float4 w = *(const float4*)(p0 + 512);
    ushort4 r = make_ushort4(f2b(0.5f * (u.x + w.x)), f2b(0.5f * (u.y + w.y)),
                             f2b(0.5f * (u.z + w.z)), f2b(0.5f * (u.w + w.w)));
    *(ushort4*)(o + (((size_t)(b * 516 + 2 + t2)) << 9) + col) = r;
}
__global__ void wtrans_k(const float* __restrict__ w, u16* __restrict__ wt, int KS) {
    const int i = blockIdx.x * 256 + threadIdx.x;
    if (i >= 512 * 512 * KS) return;
    const int o = i / (512 * KS);
    const int rem = i - o * (512 * KS);
    const int c = rem / KS, ks = rem - c * KS;
    wt[((size_t)o * KS + ks) * 512 + c] = f2b(w[i]);
}
__global__ void bnfold_k(const float* __restrict__ g, const float* __restrict__ b,
                         const float* __restrict__ m, const float* __restrict__ v,
                         const float* __restrict__ cb, float* __restrict__ sc, float* __restrict__ sh) {
    const int i = blockIdx.x * blockDim.x + threadIdx.x;
    if (i < Dm) {
        const float s = g[i] * rsqrtf(v[i] + 1e-5f);
        sc[i] = s;
        sh[i] = (cb[i] - m[i]) * s + b[i];
    }
}

// ---------------------------------------------------------------------------
extern "C" void kernel_launch(void* const* d_in, const int* in_sizes, int n_in,
                              void* d_out, int out_size, void* d_ws, size_t ws_size,
                              hipStream_t stream)
{
    (void)in_sizes; (void)n_in; (void)out_size; (void)ws_size;
    const float* poses   = (const float*)d_in[0];
    const float* embed_w = (const float*)d_in[1];
    const float* embed_b = (const float*)d_in[2];
    const float* ln0_g   = (const float*)d_in[3];
    const float* ln0_b   = (const float*)d_in[4];
    const float* inw  = (const float*)d_in[5];
    const float* inb  = (const float*)d_in[6];
    const float* outw = (const float*)d_in[7];
    const float* outb = (const float*)d_in[8];
    const float* ln1g = (const float*)d_in[9];
    const float* ln1b = (const float*)d_in[10];
    const float* ln2g = (const float*)d_in[11];
    const float* ln2b = (const float*)d_in[12];
    const float* ff1w = (const float*)d_in[13];
    const float* ff1b = (const float*)d_in[14];
    const float* ff2w = (const float*)d_in[15];
    const float* ff2b = (const float*)d_in[16];
    const float* conv1w = (const float*)d_in[17];
    const float* conv1b = (const float*)d_in[18];
    const float* bn1g = (const float*)d_in[19];
    const float* bn1b = (const float*)d_in[20];
    const float* bn1m = (const float*)d_in[21];
    const float* bn1v = (const float*)d_in[22];
    const float* conv2w = (const float*)d_in[23];
    const float* conv2b = (const float*)d_in[24];
    const float* bn2g = (const float*)d_in[25];
    const float* bn2b = (const float*)d_in[26];
    const float* bn2m = (const float*)d_in[27];
    const float* bn2v = (const float*)d_in[28];
    const float* fc1w = (const float*)d_in[29];
    const float* fc1b = (const float*)d_in[30];
    const float* fc2w = (const float*)d_in[31];
    const float* fc2b = (const float*)d_in[32];

    char* ws = (char*)d_ws;
    float* x    = (float*)(ws);                       // 8MB fp32 residual stream
    float* resb = (float*)(ws + (8u << 20));          // 8MB
    float* big  = (float*)(ws + (16u << 20));         // 24MB (qkv fp32 / embed out / tail)
    u16* hb16   = (u16*)(ws + (40u << 20));           // 4MB (LN out; also poses pad)
    u16* ctx16  = (u16*)(ws + (44u << 20));           // 4MB
    u16* ff116  = (u16*)(ws + (48u << 20));           // 16MB
    u16* wbuf   = (u16*)(ws + (64u << 20));           // 6.3MB per-layer weights
    float* outp = (float*)d_out;

    // tail buffers inside big (free there)
    char* tb = (char*)big;
    u16* poolpad = (u16*)tb;                          // [4][516][512]
    u16* c1pad   = (u16*)(tb + 2113536);              // [4][514][512]
    u16* c2o16   = (u16*)(tb + 4218880);              // [2048][512]
    u16* f1o16   = (u16*)(tb + 6316032);              // [2048][256]
    u16* w1t16   = (u16*)(tb + 7364608);              // [512][2560]
    u16* w2t16   = (u16*)(tb + 9986048);              // [512][1536]
    u16* fc1w16  = (u16*)(tb + 11558912);             // [256][512]
    u16* fc2w16  = (u16*)(tb + 11821056);             // [1296][256]
    float* sc1   = (float*)(tb + 12484608);
    float* sh1   = sc1 + 512;
    float* sc2   = sh1 + 512;
    float* sh2   = sc2 + 512;
    u16* embw16  = (u16*)(tb + (20u << 20));          // [512][256]
    u16* pospad  = hb16;                              // [4096][256]

    const u16* wq  = wbuf;
    const u16* wo  = wbuf + 786432;
    const u16* wf1 = wbuf + 1048576;
    const u16* wf2 = wbuf + 2097152;

    // ---- head: pad-convert, embed GEMM (bf16), LN + PE ----
    padposes_k<<<4096, 256, 0, stream>>>(poses, pospad, 4096);
    padposes_k<<<512, 256, 0, stream>>>(embed_w, embw16, 512);
    gemm_bf<EPI_BIAS, false, 0, 0><<<dim3(4, 32), 256, 0, stream>>>(
        pospad, 256, embw16, big, nullptr, Mseq, 512, 256, embed_b, nullptr, nullptr, nullptr);
    ln_k<false, true><<<1024, 256, 0, stream>>>(big, x, nullptr, ln0_g, ln0_b);

    // ---- transformer layers ----
    for (int i = 0; i < 8; ++i) {
        if (i == 2 || i == 4 || i == 6)
            copy_k<<<2048, 256, 0, stream>>>(x, resb, 1 << 19);
        cvt_layer_k<<<1536, 256, 0, stream>>>(inw, outw, ff1w, ff2w, i, wbuf);
        ln_k<true, false><<<1024, 256, 0, stream>>>(x, nullptr, hb16, ln1g + i * 512, ln1b + i * 512);
        gemm_bf<EPI_BIAS, false, 0, 0><<<dim3(12, 32), 256, 0, stream>>>(
            hb16, 512, wq, big, nullptr, Mseq, 1536, 512, inb + i * 1536, nullptr, nullptr, nullptr);
        attn_kernel<<<dim3(16, 8, 4), 256, 0, stream>>>(big, ctx16);
        gemm_bf<EPI_BIAS_RES, false, 0, 0><<<dim3(4, 32), 256, 0, stream>>>(
            ctx16, 512, wo, x, nullptr, Mseq, 512, 512, outb + i * 512, x, nullptr, nullptr);
        ln_k<true, false><<<1024, 256, 0, stream>>>(x, nullptr, hb16, ln2g + i * 512, ln2b + i * 512);
        gemm_bf<EPI_BIAS_RELU, true, 0, 0><<<dim3(16, 32), 256, 0, stream>>>(
            hb16, 512, wf1, nullptr, ff116, Mseq, 2048, 512, ff1b + i * 2048, nullptr, nullptr, nullptr);
        gemm_bf<EPI_BIAS_RES, false, 0, 0><<<dim3(4, 32), 256, 0, stream>>>(
            ff116, 2048, wf2, x, nullptr, Mseq, 512, 2048, ff2b + i * 512, x, nullptr, nullptr);
        if (i == 3 || i == 5 || i == 7)
            add_k<<<2048, 256, 0, stream>>>(x, resb, 1 << 19);
    }

    // ---- tail ----
    zero_k<<<516, 256, 0, stream>>>((uint4*)poolpad, 132096);
    pool_k<<<1024, 256, 0, stream>>>(x, poolpad);
    wtrans_k<<<5120, 256, 0, stream>>>(conv1w, w1t16, 5);
    bnfold_k<<<2, 256, 0, stream>>>(bn1g, bn1b, bn1m, bn1v, conv1b, sc1, sh1);
    zero_k<<<514, 256, 0, stream>>>((uint4*)c1pad, 131584);
    gemm_bf<EPI_SS_GELU, true, 2, 1><<<dim3(4, 16), 256, 0, stream>>>(
        poolpad, 512, w1t16, nullptr, c1pad, Mtc, 512, 2560, nullptr, nullptr, sc1, sh1);
    wtrans_k<<<3072, 256, 0, stream>>>(conv2w, w2t16, 3);
    bnfold_k<<<2, 256, 0, stream>>>(bn2g, bn2b, bn2m, bn2v, conv2b, sc2, sh2);
    gemm_bf<EPI_SS_GELU, true, 1, 0><<<dim3(4, 16), 256, 0, stream>>>(
        c1pad, 512, w2t16, nullptr, c2o16, Mtc, 512, 1536, nullptr, nullptr, sc2, sh2);
    cvt8_k<<<64, 256, 0, stream>>>(fc1w, fc1w16, 16384);
    cvt8_k<<<162, 256, 0, stream>>>(fc2w, fc2w16, 41472);
    gemm_bf<EPI_BIAS_GELU, true, 0, 0><<<dim3(2, 16), 256, 0, stream>>>(
        c2o16, 512, fc1w16, nullptr, f1o16, Mtc, 256, 512, fc1b, nullptr, nullptr, nullptr);
    gemm_bf<EPI_BIAS, false, 0, 0><<<dim3(11, 16), 256, 0, stream>>>(
        f1o16, 256, fc2w16, outp, nullptr, Mtc, 1296, 256, fc2b, nullptr, nullptr, nullptr);
}

// Round 3
// 1494.827 us; speedup vs baseline: 4.2398x; 1.6366x over previous
//
#include <hip/hip_runtime.h>
#include <math.h>

using u16 = unsigned short;
typedef __attribute__((ext_vector_type(8))) __bf16 bf16x8;
typedef __attribute__((ext_vector_type(4))) float f32x4;

constexpr int Bn = 4, Tn = 1024, INDIM = 231, Dm = 512, NCn = 1296;
constexpr int T2 = 512;
constexpr int Mseq = Bn * Tn;    // 4096
constexpr int Mtc  = Bn * T2;    // 2048

enum { EPI_BIAS = 0, EPI_BIAS_RELU, EPI_BIAS_RES, EPI_BIAS_GELU, EPI_SS_GELU };

__device__ __forceinline__ float gelu_exact(float x) {
    return 0.5f * x * (1.0f + erff(x * 0.70710678118654752f));
}
__device__ __forceinline__ u16 f2b(float f) {
    unsigned u = __builtin_bit_cast(unsigned, f);
    return (u16)((u + 0x7FFFu + ((u >> 16) & 1u)) >> 16);
}
__device__ __forceinline__ unsigned pack2(float a, float b) {
    return (unsigned)f2b(a) | ((unsigned)f2b(b) << 16);
}

typedef __attribute__((address_space(3))) void lds_void;
typedef __attribute__((address_space(1))) void g_void;
__device__ __forceinline__ void gld16(const void* g, void* l) {
    __builtin_amdgcn_global_load_lds((g_void*)(uintptr_t)g, (lds_void*)(uintptr_t)l, 16, 0, 0);
}

// ---------------------------------------------------------------------------
// bf16 MFMA GEMM (m97 structure). MT=128: 128x128 tile; MT=64: 64x128 tile
// (doubles grid for narrow-N GEMMs). C = A[M,K] @ W[N,K]^T + epilogue.
// ---------------------------------------------------------------------------
template<int EPI, bool OB, int IPAD, int OPAD, int MT>
__global__ __launch_bounds__(256)
void gemm_bf(const u16* __restrict__ A, int lda,
             const u16* __restrict__ W,
             float* __restrict__ Cf, u16* __restrict__ Cb,
             int M, int N, int K,
             const float* __restrict__ bias, const float* __restrict__ resid,
             const float* __restrict__ scale, const float* __restrict__ shift)
{
    constexpr int NR = (MT == 128) ? 4 : 2;
    __shared__ __align__(16) u16 As[MT * 32];
    __shared__ __align__(16) u16 Bs[128 * 32];
    const int tid = threadIdx.x;
    const int bm = blockIdx.y * MT, bn = blockIdx.x * 128;
    const int w = tid >> 6, lane = tid & 63;
    const int wr = (MT == 128) ? (w >> 1) * 64 : 0;
    const int wc = (MT == 128) ? (w & 1) * 64 : w * 32;
    const int lr = lane & 15, lhi = lane >> 4;
    const int lkb = lhi * 8;

    const int sr = tid >> 2, sk = (tid & 3) * 8;
    const int r0 = bm + sr;
    const u16* ap0 = A + (size_t)(r0 + 2 * IPAD * (r0 >> 9)) * lda + sk;
    const u16* ap1 = nullptr;
    if constexpr (MT == 128) {
        const int r1 = r0 + 64;
        ap1 = A + (size_t)(r1 + 2 * IPAD * (r1 >> 9)) * lda + sk;
    }
    int wr0 = bn + sr;      if (wr0 >= N) wr0 = N - 1;
    int wr1 = bn + 64 + sr; if (wr1 >= N) wr1 = N - 1;
    const u16* wp0 = W + (size_t)wr0 * K + sk;
    const u16* wp1 = W + (size_t)wr1 * K + sk;
    u16* la0 = &As[tid * 8];
    u16* la1 = (MT == 128) ? &As[2048 + tid * 8] : nullptr;
    u16* lb0 = &Bs[tid * 8];
    u16* lb1 = &Bs[2048 + tid * 8];

    f32x4 acc[4][NR] = {};
    const u16* arp = &As[(wr + lr) * 32 + lkb];
    const u16* brp = &Bs[(wc + lr) * 32 + lkb];

    for (int k0 = 0; k0 < K; k0 += 32) {
        gld16(ap0 + k0, la0);
        if constexpr (MT == 128) gld16(ap1 + k0, la1);
        gld16(wp0 + k0, lb0);
        gld16(wp1 + k0, lb1);
        __syncthreads();
        bf16x8 af[4], bf[NR];
#pragma unroll
        for (int m = 0; m < 4; ++m) af[m] = *(const bf16x8*)(arp + m * 512);
#pragma unroll
        for (int n = 0; n < NR; ++n) bf[n] = *(const bf16x8*)(brp + n * 512);
#pragma unroll
        for (int m = 0; m < 4; ++m)
#pragma unroll
            for (int n = 0; n < NR; ++n)
                acc[m][n] = __builtin_amdgcn_mfma_f32_16x16x32_bf16(af[m], bf[n], acc[m][n], 0, 0, 0);
        __syncthreads();
    }

    const int col0 = bn + wc + lr;
    const int row0 = bm + wr + lhi * 4;
#pragma unroll
    for (int n = 0; n < NR; ++n) {
        const int col = col0 + n * 16;
        if (col >= N) continue;
        float bv = 0.f, sv = 0.f, hv = 0.f;
        if constexpr (EPI == EPI_SS_GELU) { sv = scale[col]; hv = shift[col]; }
        else bv = bias[col];
#pragma unroll
        for (int m = 0; m < 4; ++m) {
#pragma unroll
            for (int j = 0; j < 4; ++j) {
                const int r = row0 + m * 16 + j;
                const int orow = r + OPAD * (2 * (r >> 9) + 1);
                float o = acc[m][n][j];
                if constexpr (EPI == EPI_SS_GELU) {
                    o = gelu_exact(o * sv + hv);
                } else {
                    o += bv;
                    if constexpr (EPI == EPI_BIAS_RELU) o = fmaxf(o, 0.f);
                    if constexpr (EPI == EPI_BIAS_GELU) o = gelu_exact(o);
                    if constexpr (EPI == EPI_BIAS_RES) o += resid[(size_t)r * N + col];
                }
                if constexpr (OB) Cb[(size_t)orow * N + col] = f2b(o);
                else              Cf[(size_t)orow * N + col] = o;
            }
        }
    }
}

// ---------------------------------------------------------------------------
// bf16 MFMA flash attention. qkv bf16 [B*T,1536] (q|k|v), out bf16 [B*T,512].
// grid (16,8,4), block 256 (4 waves x 16 queries). 64-key tiles.
// K via global_load_lds w/ pre-swizzled source; V reg-transposed to V^T in LDS
// (same XOR swizzle); P round-trips via padded f32 LDS to A-frag layout.
// ---------------------------------------------------------------------------
__global__ __launch_bounds__(256)
void attn_mfma(const u16* __restrict__ qkv, u16* __restrict__ out)
{
    const int b = blockIdx.z, h = blockIdx.y, q0 = blockIdx.x * 64;
    __shared__ __align__(16) u16 Ks[64 * 64];
    __shared__ __align__(16) u16 Vt[64 * 64];     // V^T [d][key]
    __shared__ __align__(16) float Ps[4][16 * 68]; // per-wave P, padded rows
    const int tid = threadIdx.x;
    const int w = tid >> 6, lane = tid & 63;
    const int lr = lane & 15, lhi = lane >> 4;

    bf16x8 qf0, qf1;
    {
        const u16* qp = qkv + (size_t)(b * Tn + q0 + w * 16 + lr) * 1536 + h * 64 + lhi * 8;
        qf0 = *(const bf16x8*)qp;
        qf1 = *(const bf16x8*)(qp + 32);
    }
    float mrow[4], lrow[4];
#pragma unroll
    for (int j = 0; j < 4; ++j) { mrow[j] = -1e30f; lrow[j] = 0.f; }
    f32x4 oacc[4] = {};

    const int kp = tid & 31, dc = (tid >> 5) * 8;  // V staging mapping

    for (int kt = 0; kt < 16; ++kt) {
        const int kbase = kt * 64;
        __syncthreads();
        // --- stage K (async, source pre-swizzled so linear LDS = swizzled layout)
#pragma unroll
        for (int i = 0; i < 2; ++i) {
            const int row = i * 32 + w * 8 + (lane >> 3);
            const int cg = (lane & 7) ^ (lane >> 3);
            gld16(qkv + (size_t)(b * Tn + kbase + row) * 1536 + 512 + h * 64 + cg * 8,
                  &Ks[(i * 256 + tid) * 8]);
        }
        // --- stage V^T (register transpose, swizzled ds_write_b32)
        {
            const u16* v0 = qkv + (size_t)(b * Tn + kbase + 2 * kp) * 1536 + 1024 + h * 64 + dc;
            const uint4 r0v = *(const uint4*)v0;
            const uint4 r1v = *(const uint4*)(v0 + 1536);
            const unsigned a0[4] = {r0v.x, r0v.y, r0v.z, r0v.w};
            const unsigned a1[4] = {r1v.x, r1v.y, r1v.z, r1v.w};
#pragma unroll
            for (int jj = 0; jj < 4; ++jj) {
                const int d0_ = dc + 2 * jj, d1_ = d0_ + 1;
                const unsigned w0 = (a0[jj] & 0xffffu) | (a1[jj] << 16);
                const unsigned w1 = (a0[jj] >> 16) | (a1[jj] & 0xffff0000u);
                *(unsigned*)((char*)Vt + d0_ * 128 + ((4 * kp) ^ ((d0_ & 7) << 4))) = w0;
                *(unsigned*)((char*)Vt + d1_ * 128 + ((4 * kp) ^ ((d1_ & 7) << 4))) = w1;
            }
        }
        __syncthreads();
        // --- QK^T: S[16q][64k] per wave
        f32x4 s[4] = {};
#pragma unroll
        for (int t = 0; t < 4; ++t) {
            const int r = t * 16 + lr;
            const int byt0 = (lhi * 16) ^ ((r & 7) << 4);
            const int byt1 = (64 + lhi * 16) ^ ((r & 7) << 4);
            const bf16x8 k0 = *(const bf16x8*)((const char*)Ks + r * 128 + byt0);
            const bf16x8 k1 = *(const bf16x8*)((const char*)Ks + r * 128 + byt1);
            s[t] = __builtin_amdgcn_mfma_f32_16x16x32_bf16(qf0, k0, s[t], 0, 0, 0);
            s[t] = __builtin_amdgcn_mfma_f32_16x16x32_bf16(qf1, k1, s[t], 0, 0, 0);
        }
        // --- online softmax (C-layout: col=key=lane&15, row=q=lhi*4+j)
        float sv[4][4];
#pragma unroll
        for (int t = 0; t < 4; ++t)
#pragma unroll
            for (int j = 0; j < 4; ++j) sv[t][j] = s[t][j] * 0.125f;
        float f[4];
#pragma unroll
        for (int j = 0; j < 4; ++j) {
            float mt = fmaxf(fmaxf(sv[0][j], sv[1][j]), fmaxf(sv[2][j], sv[3][j]));
            mt = fmaxf(mt, __shfl_xor(mt, 1));
            mt = fmaxf(mt, __shfl_xor(mt, 2));
            mt = fmaxf(mt, __shfl_xor(mt, 4));
            mt = fmaxf(mt, __shfl_xor(mt, 8));
            const float mnew = fmaxf(mrow[j], mt);
            f[j] = __expf(mrow[j] - mnew);
            mrow[j] = mnew;
            float sum = 0.f;
#pragma unroll
            for (int t = 0; t < 4; ++t) {
                sv[t][j] = __expf(sv[t][j] - mnew);
                sum += sv[t][j];
            }
            sum += __shfl_xor(sum, 1);
            sum += __shfl_xor(sum, 2);
            sum += __shfl_xor(sum, 4);
            sum += __shfl_xor(sum, 8);
            lrow[j] = lrow[j] * f[j] + sum;
        }
#pragma unroll
        for (int t = 0; t < 4; ++t)
#pragma unroll
            for (int j = 0; j < 4; ++j) oacc[t][j] *= f[j];
        // --- P -> LDS (f32, padded row 68)
#pragma unroll
        for (int t = 0; t < 4; ++t)
#pragma unroll
            for (int j = 0; j < 4; ++j)
                Ps[w][(lhi * 4 + j) * 68 + t * 16 + lr] = sv[t][j];
        __syncthreads();
        // --- P A-frags (bf16) + PV
        bf16x8 pf[2];
#pragma unroll
        for (int s2 = 0; s2 < 2; ++s2) {
            const float* pr = &Ps[w][lr * 68 + s2 * 32 + lhi * 8];
            const float4 pa = *(const float4*)pr;
            const float4 pb = *(const float4*)(pr + 4);
            uint4 pk;
            pk.x = pack2(pa.x, pa.y); pk.y = pack2(pa.z, pa.w);
            pk.z = pack2(pb.x, pb.y); pk.w = pack2(pb.z, pb.w);
            pf[s2] = __builtin_bit_cast(bf16x8, pk);
        }
#pragma unroll
        for (int t = 0; t < 4; ++t) {
            const int rd = t * 16 + lr;
            const int byt0 = (lhi * 16) ^ ((rd & 7) << 4);
            const int byt1 = (64 + lhi * 16) ^ ((rd & 7) << 4);
            const bf16x8 v0f = *(const bf16x8*)((const char*)Vt + rd * 128 + byt0);
            const bf16x8 v1f = *(const bf16x8*)((const char*)Vt + rd * 128 + byt1);
            oacc[t] = __builtin_amdgcn_mfma_f32_16x16x32_bf16(pf[0], v0f, oacc[t], 0, 0, 0);
            oacc[t] = __builtin_amdgcn_mfma_f32_16x16x32_bf16(pf[1], v1f, oacc[t], 0, 0, 0);
        }
    }
    // --- epilogue: O/l, bf16 store
#pragma unroll
    for (int j = 0; j < 4; ++j) {
        const float inv = 1.f / lrow[j];
        const size_t grow = (size_t)(b * Tn + q0 + w * 16 + lhi * 4 + j) * 512 + h * 64;
#pragma unroll
        for (int t = 0; t < 4; ++t)
            out[grow + t * 16 + lr] = f2b(oacc[t][j] * inv);
    }
}

// ---------------------------------------------------------------------------
// LayerNorm, one wave per row; PE variant writes fp32, layer variant bf16
// ---------------------------------------------------------------------------
__device__ __forceinline__ float pe_val(int t, int d) {
    const int k = d & ~1;
    const float invf = __expf(-(float)k * (9.210340371976184f / 512.f));
    const float ang = (float)t * invf;
    return (d & 1) ? cosf(ang) : sinf(ang);
}

template<bool OB, bool PE>
__global__ __launch_bounds__(256)
void ln_k(const float* __restrict__ in, float* __restrict__ outf, u16* __restrict__ outb,
          const float* __restrict__ g, const float* __restrict__ bsh)
{
    const int lane = threadIdx.x & 63;
    const int row = blockIdx.x * 4 + (threadIdx.x >> 6);
    const float* src = in + (size_t)row * Dm;
    const int c0 = lane * 4;
    const float4 v0 = *(const float4*)(src + c0);
    const float4 v1 = *(const float4*)(src + 256 + c0);
    float s  = v0.x + v0.y + v0.z + v0.w + v1.x + v1.y + v1.z + v1.w;
    float ss = v0.x * v0.x + v0.y * v0.y + v0.z * v0.z + v0.w * v0.w
             + v1.x * v1.x + v1.y * v1.y + v1.z * v1.z + v1.w * v1.w;
#pragma unroll
    for (int off = 32; off; off >>= 1) { s += __shfl_xor(s, off); ss += __shfl_xor(ss, off); }
    const float mean = s * (1.f / 512.f);
    const float var = ss * (1.f / 512.f) - mean * mean;
    const float rstd = rsqrtf(var + 1e-5f);
    const float4 g0 = *(const float4*)(g + c0),   g1 = *(const float4*)(g + 256 + c0);
    const float4 b0 = *(const float4*)(bsh + c0), b1 = *(const float4*)(bsh + 256 + c0);
    float o0[4] = {(v0.x - mean) * rstd * g0.x + b0.x, (v0.y - mean) * rstd * g0.y + b0.y,
                   (v0.z - mean) * rstd * g0.z + b0.z, (v0.w - mean) * rstd * g0.w + b0.w};
    float o1[4] = {(v1.x - mean) * rstd * g1.x + b1.x, (v1.y - mean) * rstd * g1.y + b1.y,
                   (v1.z - mean) * rstd * g1.z + b1.z, (v1.w - mean) * rstd * g1.w + b1.w};
    if constexpr (PE) {
        const int t = row & (Tn - 1);
#pragma unroll
        for (int j = 0; j < 4; ++j) { o0[j] += pe_val(t, c0 + j); o1[j] += pe_val(t, 256 + c0 + j); }
    }
    if constexpr (OB) {
        *(ushort4*)(outb + (size_t)row * Dm + c0) =
            make_ushort4(f2b(o0[0]), f2b(o0[1]), f2b(o0[2]), f2b(o0[3]));
        *(ushort4*)(outb + (size_t)row * Dm + 256 + c0) =
            make_ushort4(f2b(o1[0]), f2b(o1[1]), f2b(o1[2]), f2b(o1[3]));
    } else {
        *(float4*)(outf + (size_t)row * Dm + c0) = make_float4(o0[0], o0[1], o0[2], o0[3]);
        *(float4*)(outf + (size_t)row * Dm + 256 + c0) = make_float4(o1[0], o1[1], o1[2], o1[3]);
    }
}

// ---------------------------------------------------------------------------
// helpers
// ---------------------------------------------------------------------------
__global__ void copy_k(const float* __restrict__ a, float* __restrict__ o, int n4) {
    const int i = blockIdx.x * blockDim.x + threadIdx.x;
    if (i < n4) ((float4*)o)[i] = ((const float4*)a)[i];
}
__global__ void add_k(float* __restrict__ o, const float* __restrict__ a, int n4) {
    const int i = blockIdx.x * blockDim.x + threadIdx.x;
    if (i < n4) {
        float4 x = ((float4*)o)[i];
        const float4 y = ((const float4*)a)[i];
        x.x += y.x; x.y += y.y; x.z += y.z; x.w += y.w;
        ((float4*)o)[i] = x;
    }
}
__global__ void cvt_layer_k(const float* __restrict__ inw, const float* __restrict__ outw,
                            const float* __restrict__ ff1w, const float* __restrict__ ff2w,
                            int layer, u16* __restrict__ dst) {
    const int i = (blockIdx.x * 256 + threadIdx.x) * 8;
    const float* src;
    if (i < 786432)       src = inw  + (size_t)layer *  786432 + i;
    else if (i < 1048576) src = outw + (size_t)layer *  262144 + (i - 786432);
    else if (i < 2097152) src = ff1w + (size_t)layer * 1048576 + (i - 1048576);
    else                  src = ff2w + (size_t)layer * 1048576 + (i - 2097152);
    const float4 a = *(const float4*)src, b = *(const float4*)(src + 4);
    uint4 o; o.x = pack2(a.x, a.y); o.y = pack2(a.z, a.w); o.z = pack2(b.x, b.y); o.w = pack2(b.z, b.w);
    *(uint4*)(dst + i) = o;
}
__global__ void cvt8_k(const float* __restrict__ in, u16* __restrict__ out, int n8) {
    const int t = blockIdx.x * 256 + threadIdx.x;
    if (t >= n8) return;
    const int i = t * 8;
    const float4 a = *(const float4*)(in + i), b = *(const float4*)(in + i + 4);
    uint4 o; o.x = pack2(a.x, a.y); o.y = pack2(a.z, a.w); o.z = pack2(b.x, b.y); o.w = pack2(b.z, b.w);
    *(uint4*)(out + i) = o;
}
__global__ void padposes_k(const float* __restrict__ p, u16* __restrict__ o, int rows) {
    const int i = blockIdx.x * 256 + threadIdx.x;
    if (i >= rows * 256) return;
    const int r = i >> 8, c = i & 255;
    o[i] = (c < INDIM) ? f2b(p[r * INDIM + c]) : (u16)0;
}
__global__ void zero_k(uint4* __restrict__ p, int n16) {
    const int i = blockIdx.x * 256 + threadIdx.x;
    if (i < n16) p[i] = make_uint4(0, 0, 0, 0);
}
__global__ void pool_k(const float* __restrict__ x, u16* __restrict__ o) {
    const int i = blockIdx.x * 256 + threadIdx.x;
    if (i >= 262144) return;
    const int flat = i * 4;
    const int row = flat >> 9, col = flat & 511;
    const int b = row >> 9, t2 = row & 511;
    const float* p0 = x + ((size_t)(b * Tn + 2 * t2) << 9) + col;
    const float4 u = *(const float4*)p0;
    const float4 w = *(const float4*)(p0 + 512);
    ushort4 r = make_ushort4(f2b(0.5f * (u.x + w.x)), f2b(0.5f * (u.y + w.y)),
                             f2b(0.5f * (u.z + w.z)), f2b(0.5f * (u.w + w.w)));
    *(ushort4*)(o + (((size_t)(b * 516 + 2 + t2)) << 9) + col) = r;
}
__global__ void wtrans_k(const float* __restrict__ w, u16* __restrict__ wt, int KS) {
    const int i = blockIdx.x * 256 + threadIdx.x;
    if (i >= 512 * 512 * KS) return;
    const int o = i / (512 * KS);
    const int rem = i - o * (512 * KS);
    const int c = rem / KS, ks = rem - c * KS;
    wt[((size_t)o * KS + ks) * 512 + c] = f2b(w[i]);
}
__global__ void bnfold_k(const float* __restrict__ g, const float* __restrict__ b,
                         const float* __restrict__ m, const float* __restrict__ v,
                         const float* __restrict__ cb, float* __restrict__ sc, float* __restrict__ sh) {
    const int i = blockIdx.x * blockDim.x + threadIdx.x;
    if (i < Dm) {
        const float s = g[i] * rsqrtf(v[i] + 1e-5f);
        sc[i] = s;
        sh[i] = (cb[i] - m[i]) * s + b[i];
    }
}

// ---------------------------------------------------------------------------
extern "C" void kernel_launch(void* const* d_in, const int* in_sizes, int n_in,
                              void* d_out, int out_size, void* d_ws, size_t ws_size,
                              hipStream_t stream)
{
    (void)in_sizes; (void)n_in; (void)out_size; (void)ws_size;
    const float* poses   = (const float*)d_in[0];
    const float* embed_w = (const float*)d_in[1];
    const float* embed_b = (const float*)d_in[2];
    const float* ln0_g   = (const float*)d_in[3];
    const float* ln0_b   = (const float*)d_in[4];
    const float* inw  = (const float*)d_in[5];
    const float* inb  = (const float*)d_in[6];
    const float* outw = (const float*)d_in[7];
    const float* outb = (const float*)d_in[8];
    const float* ln1g = (const float*)d_in[9];
    const float* ln1b = (const float*)d_in[10];
    const float* ln2g = (const float*)d_in[11];
    const float* ln2b = (const float*)d_in[12];
    const float* ff1w = (const float*)d_in[13];
    const float* ff1b = (const float*)d_in[14];
    const float* ff2w = (const float*)d_in[15];
    const float* ff2b = (const float*)d_in[16];
    const float* conv1w = (const float*)d_in[17];
    const float* conv1b = (const float*)d_in[18];
    const float* bn1g = (const float*)d_in[19];
    const float* bn1b = (const float*)d_in[20];
    const float* bn1m = (const float*)d_in[21];
    const float* bn1v = (const float*)d_in[22];
    const float* conv2w = (const float*)d_in[23];
    const float* conv2b = (const float*)d_in[24];
    const float* bn2g = (const float*)d_in[25];
    const float* bn2b = (const float*)d_in[26];
    const float* bn2m = (const float*)d_in[27];
    const float* bn2v = (const float*)d_in[28];
    const float* fc1w = (const float*)d_in[29];
    const float* fc1b = (const float*)d_in[30];
    const float* fc2w = (const float*)d_in[31];
    const float* fc2b = (const float*)d_in[32];

    char* ws = (char*)d_ws;
    float* x    = (float*)(ws);                       // 8MB fp32 residual stream
    float* resb = (float*)(ws + (8u << 20));          // 8MB
    char* big   = ws + (16u << 20);                   // 24MB: embed-out fp32 / qkv16 / tail
    u16* qkv16  = (u16*)big;                          // [4096][1536] bf16 = 12MB
    u16* hb16   = (u16*)(ws + (40u << 20));           // 4MB (LN out; also poses pad)
    u16* ctx16  = (u16*)(ws + (44u << 20));           // 4MB
    u16* ff116  = (u16*)(ws + (48u << 20));           // 16MB
    u16* wbuf   = (u16*)(ws + (64u << 20));           // 6.3MB per-layer weights
    float* outp = (float*)d_out;

    // tail buffers inside big (free there)
    char* tb = big;
    u16* poolpad = (u16*)tb;                          // [4][516][512]
    u16* c1pad   = (u16*)(tb + 2113536);              // [4][514][512]
    u16* c2o16   = (u16*)(tb + 4218880);              // [2048][512]
    u16* f1o16   = (u16*)(tb + 6316032);              // [2048][256]
    u16* w1t16   = (u16*)(tb + 7364608);              // [512][2560]
    u16* w2t16   = (u16*)(tb + 9986048);              // [512][1536]
    u16* fc1w16  = (u16*)(tb + 11558912);             // [256][512]
    u16* fc2w16  = (u16*)(tb + 11821056);             // [1296][256]
    float* sc1   = (float*)(tb + 12484608);
    float* sh1   = sc1 + 512;
    float* sc2   = sh1 + 512;
    float* sh2   = sc2 + 512;
    u16* embw16  = (u16*)(tb + (20u << 20));          // [512][256]
    float* embout = (float*)(tb + (16u << 20));       // [4096][512] fp32 = 8MB
    u16* pospad  = hb16;                              // [4096][256]

    const u16* wq  = wbuf;
    const u16* wo  = wbuf + 786432;
    const u16* wf1 = wbuf + 1048576;
    const u16* wf2 = wbuf + 2097152;

    // ---- head ----
    padposes_k<<<4096, 256, 0, stream>>>(poses, pospad, 4096);
    padposes_k<<<512, 256, 0, stream>>>(embed_w, embw16, 512);
    gemm_bf<EPI_BIAS, false, 0, 0, 64><<<dim3(4, 64), 256, 0, stream>>>(
        pospad, 256, embw16, embout, nullptr, Mseq, 512, 256, embed_b, nullptr, nullptr, nullptr);
    ln_k<false, true><<<1024, 256, 0, stream>>>(embout, x, nullptr, ln0_g, ln0_b);

    // ---- transformer layers ----
    for (int i = 0; i < 8; ++i) {
        if (i == 2 || i == 4 || i == 6)
            copy_k<<<2048, 256, 0, stream>>>(x, resb, 1 << 19);
        cvt_layer_k<<<1536, 256, 0, stream>>>(inw, outw, ff1w, ff2w, i, wbuf);
        ln_k<true, false><<<1024, 256, 0, stream>>>(x, nullptr, hb16, ln1g + i * 512, ln1b + i * 512);
        gemm_bf<EPI_BIAS, true, 0, 0, 128><<<dim3(12, 32), 256, 0, stream>>>(
            hb16, 512, wq, nullptr, qkv16, Mseq, 1536, 512, inb + i * 1536, nullptr, nullptr, nullptr);
        attn_mfma<<<dim3(16, 8, 4), 256, 0, stream>>>(qkv16, ctx16);
        gemm_bf<EPI_BIAS_RES, false, 0, 0, 64><<<dim3(4, 64), 256, 0, stream>>>(
            ctx16, 512, wo, x, nullptr, Mseq, 512, 512, outb + i * 512, x, nullptr, nullptr);
        ln_k<true, false><<<1024, 256, 0, stream>>>(x, nullptr, hb16, ln2g + i * 512, ln2b + i * 512);
        gemm_bf<EPI_BIAS_RELU, true, 0, 0, 128><<<dim3(16, 32), 256, 0, stream>>>(
            hb16, 512, wf1, nullptr, ff116, Mseq, 2048, 512, ff1b + i * 2048, nullptr, nullptr, nullptr);
        gemm_bf<EPI_BIAS_RES, false, 0, 0, 64><<<dim3(4, 64), 256, 0, stream>>>(
            ff116, 2048, wf2, x, nullptr, Mseq, 512, 2048, ff2b + i * 512, x, nullptr, nullptr);
        if (i == 3 || i == 5 || i == 7)
            add_k<<<2048, 256, 0, stream>>>(x, resb, 1 << 19);
    }

    // ---- tail ----
    zero_k<<<516, 256, 0, stream>>>((uint4*)poolpad, 132096);
    pool_k<<<1024, 256, 0, stream>>>(x, poolpad);
    wtrans_k<<<5120, 256, 0, stream>>>(conv1w, w1t16, 5);
    bnfold_k<<<2, 256, 0, stream>>>(bn1g, bn1b, bn1m, bn1v, conv1b, sc1, sh1);
    zero_k<<<514, 256, 0, stream>>>((uint4*)c1pad, 131584);
    gemm_bf<EPI_SS_GELU, true, 2, 1, 64><<<dim3(4, 32), 256, 0, stream>>>(
        poolpad, 512, w1t16, nullptr, c1pad, Mtc, 512, 2560, nullptr, nullptr, sc1, sh1);
    wtrans_k<<<3072, 256, 0, stream>>>(conv2w, w2t16, 3);
    bnfold_k<<<2, 256, 0, stream>>>(bn2g, bn2b, bn2m, bn2v, conv2b, sc2, sh2);
    gemm_bf<EPI_SS_GELU, true, 1, 0, 64><<<dim3(4, 32), 256, 0, stream>>>(
        c1pad, 512, w2t16, nullptr, c2o16, Mtc, 512, 1536, nullptr, nullptr, sc2, sh2);
    cvt8_k<<<64, 256, 0, stream>>>(fc1w, fc1w16, 16384);
    cvt8_k<<<162, 256, 0, stream>>>(fc2w, fc2w16, 41472);
    gemm_bf<EPI_BIAS_GELU, true, 0, 0, 64><<<dim3(2, 32), 256, 0, stream>>>(
        c2o16, 512, fc1w16, nullptr, f1o16, Mtc, 256, 512, fc1b, nullptr, nullptr, nullptr);
    gemm_bf<EPI_BIAS, false, 0, 0, 64><<<dim3(11, 32), 256, 0, stream>>>(
        f1o16, 256, fc2w16, outp, nullptr, Mtc, 1296, 256, fc2b, nullptr, nullptr, nullptr);
}

// Round 4
// 1304.302 us; speedup vs baseline: 4.8591x; 1.1461x over previous
//
#include <hip/hip_runtime.h>
#include <math.h>

using u16 = unsigned short;
typedef __attribute__((ext_vector_type(8))) __bf16 bf16x8;
typedef __attribute__((ext_vector_type(4))) float f32x4;

constexpr int Bn = 4, Tn = 1024, INDIM = 231, Dm = 512, NCn = 1296;
constexpr int T2 = 512;
constexpr int Mseq = Bn * Tn;    // 4096
constexpr int Mtc  = Bn * T2;    // 2048

enum { EPI_BIAS = 0, EPI_BIAS_RELU, EPI_BIAS_RES, EPI_BIAS_GELU, EPI_SS_GELU };

__device__ __forceinline__ float gelu_exact(float x) {
    return 0.5f * x * (1.0f + erff(x * 0.70710678118654752f));
}
__device__ __forceinline__ u16 f2b(float f) {
    unsigned u = __builtin_bit_cast(unsigned, f);
    return (u16)((u + 0x7FFFu + ((u >> 16) & 1u)) >> 16);
}
__device__ __forceinline__ unsigned pack2(float a, float b) {
    return (unsigned)f2b(a) | ((unsigned)f2b(b) << 16);
}

typedef __attribute__((address_space(3))) void lds_void;
typedef __attribute__((address_space(1))) void g_void;
__device__ __forceinline__ void gld16(const void* g, void* l) {
    __builtin_amdgcn_global_load_lds((g_void*)(uintptr_t)g, (lds_void*)(uintptr_t)l, 16, 0, 0);
}

// ---------------------------------------------------------------------------
// bf16 MFMA GEMM: BK=64, double-buffered LDS, 1 barrier/K-step, XOR-swizzled
// LDS rows (conflict-free ds_read_b128 via pre-swizzled global source).
// MT=128: 128x128 tile; MT=64: 64x128. C = A[M,K] @ W[N,K]^T + epilogue.
// ---------------------------------------------------------------------------
template<int EPI, bool OB, int IPAD, int OPAD, int MT>
__global__ __launch_bounds__(256)
void gemm_bf(const u16* __restrict__ A, int lda,
             const u16* __restrict__ W,
             float* __restrict__ Cf, u16* __restrict__ Cb,
             int M, int N, int K,
             const float* __restrict__ bias, const float* __restrict__ resid,
             const float* __restrict__ scale, const float* __restrict__ shift)
{
    constexpr int NR = (MT == 128) ? 4 : 2;
    constexpr int AI = MT / 32;                   // A stage iterations
    __shared__ __align__(16) u16 As[2][MT * 64];
    __shared__ __align__(16) u16 Bs[2][128 * 64];
    const int tid = threadIdx.x;
    const int bm = blockIdx.y * MT, bn = blockIdx.x * 128;
    const int w = tid >> 6, lane = tid & 63;
    const int wr = (MT == 128) ? (w >> 1) * 64 : 0;
    const int wc = (MT == 128) ? (w & 1) * 64 : w * 32;
    const int lr = lane & 15, lhi = lane >> 4;

    // staging: thread -> row srow (+i*32), swizzled 16B chunk
    const int srow = tid >> 3;                    // 0..31
    const int cg8 = ((tid & 7) ^ (srow & 7)) * 8; // swizzled source col (u16)
    const u16* apg[AI];
#pragma unroll
    for (int i = 0; i < AI; ++i) {
        const int r = bm + i * 32 + srow;
        apg[i] = A + (size_t)(r + 2 * IPAD * (r >> 9)) * lda + cg8;
    }
    const u16* wpg[4];
#pragma unroll
    for (int i = 0; i < 4; ++i) {
        int r = bn + i * 32 + srow; if (r >= N) r = N - 1;
        wpg[i] = W + (size_t)r * K + cg8;
    }

    f32x4 acc[4][NR] = {};
    const int nt = K >> 6;

    // prologue stage
#pragma unroll
    for (int i = 0; i < AI; ++i) gld16(apg[i], &As[0][(i * 256 + tid) * 8]);
#pragma unroll
    for (int i = 0; i < 4; ++i)  gld16(wpg[i], &Bs[0][(i * 256 + tid) * 8]);
    __syncthreads();

    for (int t = 0; t < nt; ++t) {
        const int cur = t & 1;
        if (t + 1 < nt) {
            const int k0 = (t + 1) * 64;
#pragma unroll
            for (int i = 0; i < AI; ++i) gld16(apg[i] + k0, &As[cur ^ 1][(i * 256 + tid) * 8]);
#pragma unroll
            for (int i = 0; i < 4; ++i)  gld16(wpg[i] + k0, &Bs[cur ^ 1][(i * 256 + tid) * 8]);
        }
#pragma unroll
        for (int ks = 0; ks < 2; ++ks) {
            bf16x8 af[4], bfv[NR];
#pragma unroll
            for (int m = 0; m < 4; ++m) {
                const int R = wr + lr + m * 16;
                af[m] = *(const bf16x8*)((const char*)&As[cur][0] + R * 128 + (((ks * 4 + lhi) ^ (R & 7)) * 16));
            }
#pragma unroll
            for (int n = 0; n < NR; ++n) {
                const int R = wc + lr + n * 16;
                bfv[n] = *(const bf16x8*)((const char*)&Bs[cur][0] + R * 128 + (((ks * 4 + lhi) ^ (R & 7)) * 16));
            }
#pragma unroll
            for (int m = 0; m < 4; ++m)
#pragma unroll
                for (int n = 0; n < NR; ++n)
                    acc[m][n] = __builtin_amdgcn_mfma_f32_16x16x32_bf16(af[m], bfv[n], acc[m][n], 0, 0, 0);
        }
        if (t + 1 < nt) __syncthreads();
    }

    // epilogue: C/D layout col=lane&15, row=(lane>>4)*4+reg
    const int col0 = bn + wc + lr;
    const int row0 = bm + wr + lhi * 4;
#pragma unroll
    for (int n = 0; n < NR; ++n) {
        const int col = col0 + n * 16;
        if (col >= N) continue;
        float bv = 0.f, sv = 0.f, hv = 0.f;
        if constexpr (EPI == EPI_SS_GELU) { sv = scale[col]; hv = shift[col]; }
        else bv = bias[col];
#pragma unroll
        for (int m = 0; m < 4; ++m) {
#pragma unroll
            for (int j = 0; j < 4; ++j) {
                const int r = row0 + m * 16 + j;
                const int orow = r + OPAD * (2 * (r >> 9) + 1);
                float o = acc[m][n][j];
                if constexpr (EPI == EPI_SS_GELU) {
                    o = gelu_exact(o * sv + hv);
                } else {
                    o += bv;
                    if constexpr (EPI == EPI_BIAS_RELU) o = fmaxf(o, 0.f);
                    if constexpr (EPI == EPI_BIAS_GELU) o = gelu_exact(o);
                    if constexpr (EPI == EPI_BIAS_RES) o += resid[(size_t)r * N + col];
                }
                if constexpr (OB) Cb[(size_t)orow * N + col] = f2b(o);
                else              Cf[(size_t)orow * N + col] = o;
            }
        }
    }
}

// ---------------------------------------------------------------------------
// bf16 MFMA flash attention, double-buffered K/V, 1 barrier per 64-key tile.
// qkv bf16 [B*T,1536] (q|k|v), out bf16 [B*T,512]. grid (16,8,4), 256 thr.
// ---------------------------------------------------------------------------
__global__ __launch_bounds__(256)
void attn_mfma(const u16* __restrict__ qkv, u16* __restrict__ out)
{
    const int b = blockIdx.z, h = blockIdx.y, q0 = blockIdx.x * 64;
    __shared__ __align__(16) u16 Ks[2][64 * 64];
    __shared__ __align__(16) u16 Vt[2][64 * 64];   // V^T [d][key], swizzled
    __shared__ __align__(16) float Ps[4][16 * 68];  // per-wave P
    const int tid = threadIdx.x;
    const int w = tid >> 6, lane = tid & 63;
    const int lr = lane & 15, lhi = lane >> 4;
    const int kp = tid & 31, dc = (tid >> 5) * 8;   // V staging mapping
    const int krow = w * 8 + (lane >> 3);           // 0..31 (+i*32)
    const int kcg = (((lane & 7) ^ (lane >> 3))) * 8;

    bf16x8 qf0, qf1;
    {
        const u16* qp = qkv + (size_t)(b * Tn + q0 + w * 16 + lr) * 1536 + h * 64 + lhi * 8;
        qf0 = *(const bf16x8*)qp;
        qf1 = *(const bf16x8*)(qp + 32);
    }
    float mrow[4], lrow[4];
#pragma unroll
    for (int j = 0; j < 4; ++j) { mrow[j] = -1e30f; lrow[j] = 0.f; }
    f32x4 oacc[4] = {};

    auto stageK = [&](int kb, int bsel) {
#pragma unroll
        for (int i = 0; i < 2; ++i)
            gld16(qkv + (size_t)(b * Tn + kb + i * 32 + krow) * 1536 + 512 + h * 64 + kcg,
                  &Ks[bsel][(i * 256 + tid) * 8]);
    };
    auto loadV = [&](int kb, uint4& rA, uint4& rB) {
        const u16* vp = qkv + (size_t)(b * Tn + kb + 2 * kp) * 1536 + 1024 + h * 64 + dc;
        rA = *(const uint4*)vp;
        rB = *(const uint4*)(vp + 1536);
    };
    auto vtrans = [&](uint4 rA, uint4 rB, int bsel) {
        const unsigned a0[4] = {rA.x, rA.y, rA.z, rA.w};
        const unsigned a1[4] = {rB.x, rB.y, rB.z, rB.w};
#pragma unroll
        for (int jj = 0; jj < 4; ++jj) {
            const int d0_ = dc + 2 * jj, d1_ = d0_ + 1;
            const unsigned w0 = (a0[jj] & 0xffffu) | (a1[jj] << 16);
            const unsigned w1 = (a0[jj] >> 16) | (a1[jj] & 0xffff0000u);
            *(unsigned*)((char*)&Vt[bsel][0] + d0_ * 128 + ((4 * kp) ^ ((d0_ & 7) << 4))) = w0;
            *(unsigned*)((char*)&Vt[bsel][0] + d1_ * 128 + ((4 * kp) ^ ((d1_ & 7) << 4))) = w1;
        }
    };

    uint4 vA, vB;
    stageK(0, 0);
    loadV(0, vA, vB);
    vtrans(vA, vB, 0);
    __syncthreads();

    constexpr float C1 = 0.125f * 1.44269504f;  // scale * log2(e)

    for (int kt = 0; kt < 16; ++kt) {
        const int cur = kt & 1;
        const bool more = kt < 15;
        if (more) {
            stageK((kt + 1) * 64, cur ^ 1);     // async into other buffer
            loadV((kt + 1) * 64, vA, vB);       // issue early, write late (T14)
        }
        // --- QK^T: S[16q][64k] per wave
        __builtin_amdgcn_s_setprio(1);
        f32x4 s[4] = {};
#pragma unroll
        for (int t = 0; t < 4; ++t) {
            const int r = t * 16 + lr;
            const bf16x8 k0 = *(const bf16x8*)((const char*)&Ks[cur][0] + r * 128 + ((lhi * 16) ^ ((r & 7) << 4)));
            const bf16x8 k1 = *(const bf16x8*)((const char*)&Ks[cur][0] + r * 128 + ((64 + lhi * 16) ^ ((r & 7) << 4)));
            s[t] = __builtin_amdgcn_mfma_f32_16x16x32_bf16(qf0, k0, s[t], 0, 0, 0);
            s[t] = __builtin_amdgcn_mfma_f32_16x16x32_bf16(qf1, k1, s[t], 0, 0, 0);
        }
        __builtin_amdgcn_s_setprio(0);
        // --- online softmax in exp2 domain (scale folded into one fma)
        float f[4];
#pragma unroll
        for (int j = 0; j < 4; ++j) {
            float mt = fmaxf(fmaxf(s[0][j], s[1][j]), fmaxf(s[2][j], s[3][j]));
            mt = fmaxf(mt, __shfl_xor(mt, 1));
            mt = fmaxf(mt, __shfl_xor(mt, 2));
            mt = fmaxf(mt, __shfl_xor(mt, 4));
            mt = fmaxf(mt, __shfl_xor(mt, 8));
            const float mnew = fmaxf(mrow[j], mt);
            f[j] = exp2f((mrow[j] - mnew) * C1);
            mrow[j] = mnew;
            const float nb = mnew * C1;
            float sum = 0.f;
#pragma unroll
            for (int t = 0; t < 4; ++t) {
                const float p = exp2f(fmaf(s[t][j], C1, -nb));
                Ps[w][(lhi * 4 + j) * 68 + t * 16 + lr] = p;
                sum += p;
            }
            sum += __shfl_xor(sum, 1);
            sum += __shfl_xor(sum, 2);
            sum += __shfl_xor(sum, 4);
            sum += __shfl_xor(sum, 8);
            lrow[j] = lrow[j] * f[j] + sum;
        }
#pragma unroll
        for (int t = 0; t < 4; ++t)
#pragma unroll
            for (int j = 0; j < 4; ++j) oacc[t][j] *= f[j];
        // --- P A-frags (per-wave LDS roundtrip; in-wave DS order, no barrier)
        asm volatile("s_waitcnt lgkmcnt(0)" ::: "memory");
        bf16x8 pf[2];
#pragma unroll
        for (int s2 = 0; s2 < 2; ++s2) {
            const float* pr = &Ps[w][lr * 68 + s2 * 32 + lhi * 8];
            const float4 pa = *(const float4*)pr;
            const float4 pb = *(const float4*)(pr + 4);
            uint4 pk;
            pk.x = pack2(pa.x, pa.y); pk.y = pack2(pa.z, pa.w);
            pk.z = pack2(pb.x, pb.y); pk.w = pack2(pb.z, pb.w);
            pf[s2] = __builtin_bit_cast(bf16x8, pk);
        }
        // --- PV
        __builtin_amdgcn_s_setprio(1);
#pragma unroll
        for (int t = 0; t < 4; ++t) {
            const int rd = t * 16 + lr;
            const bf16x8 v0f = *(const bf16x8*)((const char*)&Vt[cur][0] + rd * 128 + ((lhi * 16) ^ ((rd & 7) << 4)));
            const bf16x8 v1f = *(const bf16x8*)((const char*)&Vt[cur][0] + rd * 128 + ((64 + lhi * 16) ^ ((rd & 7) << 4)));
            oacc[t] = __builtin_amdgcn_mfma_f32_16x16x32_bf16(pf[0], v0f, oacc[t], 0, 0, 0);
            oacc[t] = __builtin_amdgcn_mfma_f32_16x16x32_bf16(pf[1], v1f, oacc[t], 0, 0, 0);
        }
        __builtin_amdgcn_s_setprio(0);
        if (more) {
            vtrans(vA, vB, cur ^ 1);            // late write of prefetched V
            __syncthreads();
        }
    }
    // --- epilogue
#pragma unroll
    for (int j = 0; j < 4; ++j) {
        const float inv = 1.f / lrow[j];
        const size_t grow = (size_t)(b * Tn + q0 + w * 16 + lhi * 4 + j) * 512 + h * 64;
#pragma unroll
        for (int t = 0; t < 4; ++t)
            out[grow + t * 16 + lr] = f2b(oacc[t][j] * inv);
    }
}

// ---------------------------------------------------------------------------
// LayerNorm, one wave per row; PE variant writes fp32, layer variant bf16
// ---------------------------------------------------------------------------
__device__ __forceinline__ float pe_val(int t, int d) {
    const int k = d & ~1;
    const float invf = __expf(-(float)k * (9.210340371976184f / 512.f));
    const float ang = (float)t * invf;
    return (d & 1) ? cosf(ang) : sinf(ang);
}

template<bool OB, bool PE>
__global__ __launch_bounds__(256)
void ln_k(const float* __restrict__ in, float* __restrict__ outf, u16* __restrict__ outb,
          const float* __restrict__ g, const float* __restrict__ bsh)
{
    const int lane = threadIdx.x & 63;
    const int row = blockIdx.x * 4 + (threadIdx.x >> 6);
    const float* src = in + (size_t)row * Dm;
    const int c0 = lane * 4;
    const float4 v0 = *(const float4*)(src + c0);
    const float4 v1 = *(const float4*)(src + 256 + c0);
    float s  = v0.x + v0.y + v0.z + v0.w + v1.x + v1.y + v1.z + v1.w;
    float ss = v0.x * v0.x + v0.y * v0.y + v0.z * v0.z + v0.w * v0.w
             + v1.x * v1.x + v1.y * v1.y + v1.z * v1.z + v1.w * v1.w;
#pragma unroll
    for (int off = 32; off; off >>= 1) { s += __shfl_xor(s, off); ss += __shfl_xor(ss, off); }
    const float mean = s * (1.f / 512.f);
    const float var = ss * (1.f / 512.f) - mean * mean;
    const float rstd = rsqrtf(var + 1e-5f);
    const float4 g0 = *(const float4*)(g + c0),   g1 = *(const float4*)(g + 256 + c0);
    const float4 b0 = *(const float4*)(bsh + c0), b1 = *(const float4*)(bsh + 256 + c0);
    float o0[4] = {(v0.x - mean) * rstd * g0.x + b0.x, (v0.y - mean) * rstd * g0.y + b0.y,
                   (v0.z - mean) * rstd * g0.z + b0.z, (v0.w - mean) * rstd * g0.w + b0.w};
    float o1[4] = {(v1.x - mean) * rstd * g1.x + b1.x, (v1.y - mean) * rstd * g1.y + b1.y,
                   (v1.z - mean) * rstd * g1.z + b1.z, (v1.w - mean) * rstd * g1.w + b1.w};
    if constexpr (PE) {
        const int t = row & (Tn - 1);
#pragma unroll
        for (int j = 0; j < 4; ++j) { o0[j] += pe_val(t, c0 + j); o1[j] += pe_val(t, 256 + c0 + j); }
    }
    if constexpr (OB) {
        *(ushort4*)(outb + (size_t)row * Dm + c0) =
            make_ushort4(f2b(o0[0]), f2b(o0[1]), f2b(o0[2]), f2b(o0[3]));
        *(ushort4*)(outb + (size_t)row * Dm + 256 + c0) =
            make_ushort4(f2b(o1[0]), f2b(o1[1]), f2b(o1[2]), f2b(o1[3]));
    } else {
        *(float4*)(outf + (size_t)row * Dm + c0) = make_float4(o0[0], o0[1], o0[2], o0[3]);
        *(float4*)(outf + (size_t)row * Dm + 256 + c0) = make_float4(o1[0], o1[1], o1[2], o1[3]);
    }
}

// ---------------------------------------------------------------------------
// helpers
// ---------------------------------------------------------------------------
__global__ void copy_k(const float* __restrict__ a, float* __restrict__ o, int n4) {
    const int i = blockIdx.x * blockDim.x + threadIdx.x;
    if (i < n4) ((float4*)o)[i] = ((const float4*)a)[i];
}
__global__ void add_k(float* __restrict__ o, const float* __restrict__ a, int n4) {
    const int i = blockIdx.x * blockDim.x + threadIdx.x;
    if (i < n4) {
        float4 x = ((float4*)o)[i];
        const float4 y = ((const float4*)a)[i];
        x.x += y.x; x.y += y.y; x.z += y.z; x.w += y.w;
        ((float4*)o)[i] = x;
    }
}
__global__ void cvt_layer_k(const float* __restrict__ inw, const float* __restrict__ outw,
                            const float* __restrict__ ff1w, const float* __restrict__ ff2w,
                            int layer, u16* __restrict__ dst) {
    const int i = (blockIdx.x * 256 + threadIdx.x) * 8;
    const float* src;
    if (i < 786432)       src = inw  + (size_t)layer *  786432 + i;
    else if (i < 1048576) src = outw + (size_t)layer *  262144 + (i - 786432);
    else if (i < 2097152) src = ff1w + (size_t)layer * 1048576 + (i - 1048576);
    else                  src = ff2w + (size_t)layer * 1048576 + (i - 2097152);
    const float4 a = *(const float4*)src, b = *(const float4*)(src + 4);
    uint4 o; o.x = pack2(a.x, a.y); o.y = pack2(a.z, a.w); o.z = pack2(b.x, b.y); o.w = pack2(b.z, b.w);
    *(uint4*)(dst + i) = o;
}
__global__ void cvt8_k(const float* __restrict__ in, u16* __restrict__ out, int n8) {
    const int t = blockIdx.x * 256 + threadIdx.x;
    if (t >= n8) return;
    const int i = t * 8;
    const float4 a = *(const float4*)(in + i), b = *(const float4*)(in + i + 4);
    uint4 o; o.x = pack2(a.x, a.y); o.y = pack2(a.z, a.w); o.z = pack2(b.x, b.y); o.w = pack2(b.z, b.w);
    *(uint4*)(out + i) = o;
}
__global__ void padposes_k(const float* __restrict__ p, u16* __restrict__ o, int rows) {
    const int i = blockIdx.x * 256 + threadIdx.x;
    if (i >= rows * 256) return;
    const int r = i >> 8, c = i & 255;
    o[i] = (c < INDIM) ? f2b(p[r * INDIM + c]) : (u16)0;
}
__global__ void zero_k(uint4* __restrict__ p, int n16) {
    const int i = blockIdx.x * 256 + threadIdx.x;
    if (i < n16) p[i] = make_uint4(0, 0, 0, 0);
}
__global__ void pool_k(const float* __restrict__ x, u16* __restrict__ o) {
    const int i = blockIdx.x * 256 + threadIdx.x;
    if (i >= 262144) return;
    const int flat = i * 4;
    const int row = flat >> 9, col = flat & 511;
    const int b = row >> 9, t2 = row & 511;
    const float* p0 = x + ((size_t)(b * Tn + 2 * t2) << 9) + col;
    const float4 u = *(const float4*)p0;
    const float4 w = *(const float4*)(p0 + 512);
    ushort4 r = make_ushort4(f2b(0.5f * (u.x + w.x)), f2b(0.5f * (u.y + w.y)),
                             f2b(0.5f * (u.z + w.z)), f2b(0.5f * (u.w + w.w)));
    *(ushort4*)(o + (((size_t)(b * 516 + 2 + t2)) << 9) + col) = r;
}
__global__ void wtrans_k(const float* __restrict__ w, u16* __restrict__ wt, int KS) {
    const int i = blockIdx.x * 256 + threadIdx.x;
    if (i >= 512 * 512 * KS) return;
    const int o = i / (512 * KS);
    const int rem = i - o * (512 * KS);
    const int c = rem / KS, ks = rem - c * KS;
    wt[((size_t)o * KS + ks) * 512 + c] = f2b(w[i]);
}
__global__ void bnfold_k(const float* __restrict__ g, const float* __restrict__ b,
                         const float* __restrict__ m, const float* __restrict__ v,
                         const float* __restrict__ cb, float* __restrict__ sc, float* __restrict__ sh) {
    const int i = blockIdx.x * blockDim.x + threadIdx.x;
    if (i < Dm) {
        const float s = g[i] * rsqrtf(v[i] + 1e-5f);
        sc[i] = s;
        sh[i] = (cb[i] - m[i]) * s + b[i];
    }
}

// ---------------------------------------------------------------------------
extern "C" void kernel_launch(void* const* d_in, const int* in_sizes, int n_in,
                              void* d_out, int out_size, void* d_ws, size_t ws_size,
                              hipStream_t stream)
{
    (void)in_sizes; (void)n_in; (void)out_size; (void)ws_size;
    const float* poses   = (const float*)d_in[0];
    const float* embed_w = (const float*)d_in[1];
    const float* embed_b = (const float*)d_in[2];
    const float* ln0_g   = (const float*)d_in[3];
    const float* ln0_b   = (const float*)d_in[4];
    const float* inw  = (const float*)d_in[5];
    const float* inb  = (const float*)d_in[6];
    const float* outw = (const float*)d_in[7];
    const float* outb = (const float*)d_in[8];
    const float* ln1g = (const float*)d_in[9];
    const float* ln1b = (const float*)d_in[10];
    const float* ln2g = (const float*)d_in[11];
    const float* ln2b = (const float*)d_in[12];
    const float* ff1w = (const float*)d_in[13];
    const float* ff1b = (const float*)d_in[14];
    const float* ff2w = (const float*)d_in[15];
    const float* ff2b = (const float*)d_in[16];
    const float* conv1w = (const float*)d_in[17];
    const float* conv1b = (const float*)d_in[18];
    const float* bn1g = (const float*)d_in[19];
    const float* bn1b = (const float*)d_in[20];
    const float* bn1m = (const float*)d_in[21];
    const float* bn1v = (const float*)d_in[22];
    const float* conv2w = (const float*)d_in[23];
    const float* conv2b = (const float*)d_in[24];
    const float* bn2g = (const float*)d_in[25];
    const float* bn2b = (const float*)d_in[26];
    const float* bn2m = (const float*)d_in[27];
    const float* bn2v = (const float*)d_in[28];
    const float* fc1w = (const float*)d_in[29];
    const float* fc1b = (const float*)d_in[30];
    const float* fc2w = (const float*)d_in[31];
    const float* fc2b = (const float*)d_in[32];

    char* ws = (char*)d_ws;
    float* x    = (float*)(ws);                       // 8MB fp32 residual stream
    float* resb = (float*)(ws + (8u << 20));          // 8MB
    char* big   = ws + (16u << 20);                   // 24MB: qkv16 / embed out / tail
    u16* qkv16  = (u16*)big;                          // [4096][1536] bf16 = 12MB
    u16* hb16   = (u16*)(ws + (40u << 20));           // 4MB (LN out; also poses pad)
    u16* ctx16  = (u16*)(ws + (44u << 20));           // 4MB
    u16* ff116  = (u16*)(ws + (48u << 20));           // 16MB
    u16* wbuf   = (u16*)(ws + (64u << 20));           // 6.3MB per-layer weights
    float* outp = (float*)d_out;

    // tail buffers inside big
    char* tb = big;
    u16* poolpad = (u16*)tb;                          // [4][516][512]
    u16* c1pad   = (u16*)(tb + 2113536);              // [4][514][512]
    u16* c2o16   = (u16*)(tb + 4218880);              // [2048][512]
    u16* f1o16   = (u16*)(tb + 6316032);              // [2048][256]
    u16* w1t16   = (u16*)(tb + 7364608);              // [512][2560]
    u16* w2t16   = (u16*)(tb + 9986048);              // [512][1536]
    u16* fc1w16  = (u16*)(tb + 11558912);             // [256][512]
    u16* fc2w16  = (u16*)(tb + 11821056);             // [1296][256]
    float* sc1   = (float*)(tb + 12484608);
    float* sh1   = sc1 + 512;
    float* sc2   = sh1 + 512;
    float* sh2   = sc2 + 512;
    u16* embw16  = (u16*)(tb + (20u << 20));          // [512][256]
    float* embout = (float*)(tb + (16u << 20));       // [4096][512] fp32
    u16* pospad  = hb16;                              // [4096][256]

    const u16* wq  = wbuf;
    const u16* wo  = wbuf + 786432;
    const u16* wf1 = wbuf + 1048576;
    const u16* wf2 = wbuf + 2097152;

    // ---- head ----
    padposes_k<<<4096, 256, 0, stream>>>(poses, pospad, 4096);
    padposes_k<<<512, 256, 0, stream>>>(embed_w, embw16, 512);
    gemm_bf<EPI_BIAS, false, 0, 0, 64><<<dim3(4, 64), 256, 0, stream>>>(
        pospad, 256, embw16, embout, nullptr, Mseq, 512, 256, embed_b, nullptr, nullptr, nullptr);
    ln_k<false, true><<<1024, 256, 0, stream>>>(embout, x, nullptr, ln0_g, ln0_b);

    // ---- transformer layers ----
    for (int i = 0; i < 8; ++i) {
        if (i == 2 || i == 4 || i == 6)
            copy_k<<<2048, 256, 0, stream>>>(x, resb, 1 << 19);
        cvt_layer_k<<<1536, 256, 0, stream>>>(inw, outw, ff1w, ff2w, i, wbuf);
        ln_k<true, false><<<1024, 256, 0, stream>>>(x, nullptr, hb16, ln1g + i * 512, ln1b + i * 512);
        gemm_bf<EPI_BIAS, true, 0, 0, 128><<<dim3(12, 32), 256, 0, stream>>>(
            hb16, 512, wq, nullptr, qkv16, Mseq, 1536, 512, inb + i * 1536, nullptr, nullptr, nullptr);
        attn_mfma<<<dim3(16, 8, 4), 256, 0, stream>>>(qkv16, ctx16);
        gemm_bf<EPI_BIAS_RES, false, 0, 0, 64><<<dim3(4, 64), 256, 0, stream>>>(
            ctx16, 512, wo, x, nullptr, Mseq, 512, 512, outb + i * 512, x, nullptr, nullptr);
        ln_k<true, false><<<1024, 256, 0, stream>>>(x, nullptr, hb16, ln2g + i * 512, ln2b + i * 512);
        gemm_bf<EPI_BIAS_RELU, true, 0, 0, 128><<<dim3(16, 32), 256, 0, stream>>>(
            hb16, 512, wf1, nullptr, ff116, Mseq, 2048, 512, ff1b + i * 2048, nullptr, nullptr, nullptr);
        gemm_bf<EPI_BIAS_RES, false, 0, 0, 64><<<dim3(4, 64), 256, 0, stream>>>(
            ff116, 2048, wf2, x, nullptr, Mseq, 512, 2048, ff2b + i * 512, x, nullptr, nullptr);
        if (i == 3 || i == 5 || i == 7)
            add_k<<<2048, 256, 0, stream>>>(x, resb, 1 << 19);
    }

    // ---- tail ----
    zero_k<<<516, 256, 0, stream>>>((uint4*)poolpad, 132096);
    pool_k<<<1024, 256, 0, stream>>>(x, poolpad);
    wtrans_k<<<5120, 256, 0, stream>>>(conv1w, w1t16, 5);
    bnfold_k<<<2, 256, 0, stream>>>(bn1g, bn1b, bn1m, bn1v, conv1b, sc1, sh1);
    zero_k<<<514, 256, 0, stream>>>((uint4*)c1pad, 131584);
    gemm_bf<EPI_SS_GELU, true, 2, 1, 64><<<dim3(4, 32), 256, 0, stream>>>(
        poolpad, 512, w1t16, nullptr, c1pad, Mtc, 512, 2560, nullptr, nullptr, sc1, sh1);
    wtrans_k<<<3072, 256, 0, stream>>>(conv2w, w2t16, 3);
    bnfold_k<<<2, 256, 0, stream>>>(bn2g, bn2b, bn2m, bn2v, conv2b, sc2, sh2);
    gemm_bf<EPI_SS_GELU, true, 1, 0, 64><<<dim3(4, 32), 256, 0, stream>>>(
        c1pad, 512, w2t16, nullptr, c2o16, Mtc, 512, 1536, nullptr, nullptr, sc2, sh2);
    cvt8_k<<<64, 256, 0, stream>>>(fc1w, fc1w16, 16384);
    cvt8_k<<<162, 256, 0, stream>>>(fc2w, fc2w16, 41472);
    gemm_bf<EPI_BIAS_GELU, true, 0, 0, 64><<<dim3(2, 32), 256, 0, stream>>>(
        c2o16, 512, fc1w16, nullptr, f1o16, Mtc, 256, 512, fc1b, nullptr, nullptr, nullptr);
    gemm_bf<EPI_BIAS, false, 0, 0, 64><<<dim3(11, 32), 256, 0, stream>>>(
        f1o16, 256, fc2w16, outp, nullptr, Mtc, 1296, 256, fc2b, nullptr, nullptr, nullptr);
}

// Round 5
// 1203.258 us; speedup vs baseline: 5.2671x; 1.0840x over previous
//
#include <hip/hip_runtime.h>
#include <math.h>

using u16 = unsigned short;
typedef __attribute__((ext_vector_type(8))) __bf16 bf16x8;
typedef __attribute__((ext_vector_type(4))) float f32x4;

constexpr int Bn = 4, Tn = 1024, INDIM = 231, Dm = 512, NCn = 1296;
constexpr int T2 = 512;
constexpr int Mseq = Bn * Tn;    // 4096
constexpr int Mtc  = Bn * T2;    // 2048

enum { EPI_BIAS = 0, EPI_BIAS_RELU, EPI_BIAS_RES, EPI_BIAS_GELU, EPI_SS_GELU };

__device__ __forceinline__ float gelu_exact(float x) {
    return 0.5f * x * (1.0f + erff(x * 0.70710678118654752f));
}
__device__ __forceinline__ u16 f2b(float f) {
    unsigned u = __builtin_bit_cast(unsigned, f);
    return (u16)((u + 0x7FFFu + ((u >> 16) & 1u)) >> 16);
}
__device__ __forceinline__ unsigned pack2(float a, float b) {
    return (unsigned)f2b(a) | ((unsigned)f2b(b) << 16);
}

typedef __attribute__((address_space(3))) void lds_void;
typedef __attribute__((address_space(1))) void g_void;
__device__ __forceinline__ void gld16(const void* g, void* l) {
    __builtin_amdgcn_global_load_lds((g_void*)(uintptr_t)g, (lds_void*)(uintptr_t)l, 16, 0, 0);
}

// ---------------------------------------------------------------------------
// bf16 MFMA GEMM: BK=64, double-buffered LDS, 1 barrier/K-step, XOR-swizzled
// LDS rows. MT=128: 128x128 tile; MT=64: 64x128. C = A @ W^T + epilogue.
// RM bit0: add rb (second residual); RM bit1: also store result to rbw.
// ---------------------------------------------------------------------------
template<int EPI, bool OB, int IPAD, int OPAD, int MT, int RM>
__global__ __launch_bounds__(256)
void gemm_bf(const u16* __restrict__ A, int lda,
             const u16* __restrict__ W,
             float* __restrict__ Cf, u16* __restrict__ Cb,
             int M, int N, int K,
             const float* __restrict__ bias, const float* __restrict__ resid,
             const float* __restrict__ scale, const float* __restrict__ shift,
             const float* __restrict__ rb, float* __restrict__ rbw)
{
    constexpr int NR = (MT == 128) ? 4 : 2;
    constexpr int AI = MT / 32;
    __shared__ __align__(16) u16 As[2][MT * 64];
    __shared__ __align__(16) u16 Bs[2][128 * 64];
    const int tid = threadIdx.x;
    const int bm = blockIdx.y * MT, bn = blockIdx.x * 128;
    const int w = tid >> 6, lane = tid & 63;
    const int wr = (MT == 128) ? (w >> 1) * 64 : 0;
    const int wc = (MT == 128) ? (w & 1) * 64 : w * 32;
    const int lr = lane & 15, lhi = lane >> 4;

    const int srow = tid >> 3;
    const int cg8 = ((tid & 7) ^ (srow & 7)) * 8;
    const u16* apg[AI];
#pragma unroll
    for (int i = 0; i < AI; ++i) {
        const int r = bm + i * 32 + srow;
        apg[i] = A + (size_t)(r + 2 * IPAD * (r >> 9)) * lda + cg8;
    }
    const u16* wpg[4];
#pragma unroll
    for (int i = 0; i < 4; ++i) {
        int r = bn + i * 32 + srow; if (r >= N) r = N - 1;
        wpg[i] = W + (size_t)r * K + cg8;
    }

    f32x4 acc[4][NR] = {};
    const int nt = K >> 6;

#pragma unroll
    for (int i = 0; i < AI; ++i) gld16(apg[i], &As[0][(i * 256 + tid) * 8]);
#pragma unroll
    for (int i = 0; i < 4; ++i)  gld16(wpg[i], &Bs[0][(i * 256 + tid) * 8]);
    __syncthreads();

    for (int t = 0; t < nt; ++t) {
        const int cur = t & 1;
        if (t + 1 < nt) {
            const int k0 = (t + 1) * 64;
#pragma unroll
            for (int i = 0; i < AI; ++i) gld16(apg[i] + k0, &As[cur ^ 1][(i * 256 + tid) * 8]);
#pragma unroll
            for (int i = 0; i < 4; ++i)  gld16(wpg[i] + k0, &Bs[cur ^ 1][(i * 256 + tid) * 8]);
        }
#pragma unroll
        for (int ks = 0; ks < 2; ++ks) {
            bf16x8 af[4], bfv[NR];
#pragma unroll
            for (int m = 0; m < 4; ++m) {
                const int R = wr + lr + m * 16;
                af[m] = *(const bf16x8*)((const char*)&As[cur][0] + R * 128 + (((ks * 4 + lhi) ^ (R & 7)) * 16));
            }
#pragma unroll
            for (int n = 0; n < NR; ++n) {
                const int R = wc + lr + n * 16;
                bfv[n] = *(const bf16x8*)((const char*)&Bs[cur][0] + R * 128 + (((ks * 4 + lhi) ^ (R & 7)) * 16));
            }
#pragma unroll
            for (int m = 0; m < 4; ++m)
#pragma unroll
                for (int n = 0; n < NR; ++n)
                    acc[m][n] = __builtin_amdgcn_mfma_f32_16x16x32_bf16(af[m], bfv[n], acc[m][n], 0, 0, 0);
        }
        if (t + 1 < nt) __syncthreads();
    }

    const int col0 = bn + wc + lr;
    const int row0 = bm + wr + lhi * 4;
#pragma unroll
    for (int n = 0; n < NR; ++n) {
        const int col = col0 + n * 16;
        if (col >= N) continue;
        float bv = 0.f, sv = 0.f, hv = 0.f;
        if constexpr (EPI == EPI_SS_GELU) { sv = scale[col]; hv = shift[col]; }
        else bv = bias[col];
#pragma unroll
        for (int m = 0; m < 4; ++m) {
#pragma unroll
            for (int j = 0; j < 4; ++j) {
                const int r = row0 + m * 16 + j;
                const int orow = r + OPAD * (2 * (r >> 9) + 1);
                float o = acc[m][n][j];
                if constexpr (EPI == EPI_SS_GELU) {
                    o = gelu_exact(o * sv + hv);
                } else {
                    o += bv;
                    if constexpr (EPI == EPI_BIAS_RELU) o = fmaxf(o, 0.f);
                    if constexpr (EPI == EPI_BIAS_GELU) o = gelu_exact(o);
                    if constexpr (EPI == EPI_BIAS_RES) {
                        o += resid[(size_t)r * N + col];
                        if constexpr ((RM & 1) != 0) o += rb[(size_t)r * N + col];
                    }
                }
                if constexpr ((RM & 2) != 0) rbw[(size_t)r * N + col] = o;
                if constexpr (OB) Cb[(size_t)orow * N + col] = f2b(o);
                else              Cf[(size_t)orow * N + col] = o;
            }
        }
    }
}

// ---------------------------------------------------------------------------
// bf16 MFMA flash attention, swapped-operand softmax (scores lane-local).
// qkv bf16 [B*T,1536] (q|k|v), out bf16 [B*T,512]. grid 512x1, 256 thr.
// Block decode groups all 16 q-tiles of one (b,h) onto one XCD.
// ---------------------------------------------------------------------------
__global__ __launch_bounds__(256)
void attn_mfma(const u16* __restrict__ qkv, u16* __restrict__ out)
{
    const int bid = blockIdx.x;
    const int qt = bid >> 5, g = bid & 31;       // 16 qt x 32 groups; xcd = g%8
    const int h = g & 7, b = g >> 3;
    const int q0 = qt * 64;
    __shared__ __align__(16) u16 Ks[2][64 * 64];
    __shared__ __align__(16) u16 Vt[2][64 * 64];   // V^T [d][key], swizzled
    const int tid = threadIdx.x;
    const int w = tid >> 6, lane = tid & 63;
    const int lr = lane & 15, lhi = lane >> 4;
    const int kp = tid & 31, dc = (tid >> 5) * 8;  // V staging mapping
    const int krow = tid >> 3;                     // 0..31 (+i*32)
    const int kcg = ((lane & 7) ^ (lane >> 3)) * 8;

    // Q as B-frag: lane holds Q[q = w*16+lr][d = lhi*8..+7 (+32)]
    bf16x8 qf0, qf1;
    {
        const u16* qp = qkv + (size_t)(b * Tn + q0 + w * 16 + lr) * 1536 + h * 64 + lhi * 8;
        qf0 = *(const bf16x8*)qp;
        qf1 = *(const bf16x8*)(qp + 32);
    }
    float mrow = -1e30f, lrow = 0.f;
    f32x4 oacc[4] = {};   // oacc[t][j] = O[d = 16t+4lhi+j][q = lr]

    auto stageK = [&](int kb, int bsel) {
#pragma unroll
        for (int i = 0; i < 2; ++i)
            gld16(qkv + (size_t)(b * Tn + kb + i * 32 + krow) * 1536 + 512 + h * 64 + kcg,
                  &Ks[bsel][(i * 256 + tid) * 8]);
    };
    auto loadV = [&](int kb, uint4& rA, uint4& rB) {
        const u16* vp = qkv + (size_t)(b * Tn + kb + 2 * kp) * 1536 + 1024 + h * 64 + dc;
        rA = *(const uint4*)vp;
        rB = *(const uint4*)(vp + 1536);
    };
    auto vtrans = [&](uint4 rA, uint4 rB, int bsel) {
        const unsigned a0[4] = {rA.x, rA.y, rA.z, rA.w};
        const unsigned a1[4] = {rB.x, rB.y, rB.z, rB.w};
#pragma unroll
        for (int jj = 0; jj < 4; ++jj) {
            const int d0_ = dc + 2 * jj, d1_ = d0_ + 1;
            const unsigned w0 = (a0[jj] & 0xffffu) | (a1[jj] << 16);
            const unsigned w1 = (a0[jj] >> 16) | (a1[jj] & 0xffff0000u);
            *(unsigned*)((char*)&Vt[bsel][0] + d0_ * 128 + ((4 * kp) ^ ((d0_ & 7) << 4))) = w0;
            *(unsigned*)((char*)&Vt[bsel][0] + d1_ * 128 + ((4 * kp) ^ ((d1_ & 7) << 4))) = w1;
        }
    };

    uint4 vA, vB;
    stageK(0, 0);
    loadV(0, vA, vB);
    vtrans(vA, vB, 0);
    __syncthreads();

    constexpr float C1 = 0.125f * 1.44269504f;  // scale * log2(e)

    for (int kt = 0; kt < 16; ++kt) {
        const int cur = kt & 1;
        const bool more = kt < 15;
        if (more) {
            stageK((kt + 1) * 64, cur ^ 1);
            loadV((kt + 1) * 64, vA, vB);
        }
        // --- QK^T swapped: s[t] = mfma(K_frag, Q_frag) -> C[key][q]
        __builtin_amdgcn_s_setprio(1);
        f32x4 s[4] = {};
#pragma unroll
        for (int t = 0; t < 4; ++t) {
            const int r = t * 16 + lr;
            const bf16x8 k0 = *(const bf16x8*)((const char*)&Ks[cur][0] + r * 128 + ((lhi * 16) ^ ((r & 7) << 4)));
            const bf16x8 k1 = *(const bf16x8*)((const char*)&Ks[cur][0] + r * 128 + ((64 + lhi * 16) ^ ((r & 7) << 4)));
            s[t] = __builtin_amdgcn_mfma_f32_16x16x32_bf16(k0, qf0, s[t], 0, 0, 0);
            s[t] = __builtin_amdgcn_mfma_f32_16x16x32_bf16(k1, qf1, s[t], 0, 0, 0);
        }
        __builtin_amdgcn_s_setprio(0);
        // --- in-register softmax: lane holds 16 scores of query lr
        float mt = fmaxf(fmaxf(fmaxf(s[0][0], s[0][1]), fmaxf(s[0][2], s[0][3])),
                         fmaxf(fmaxf(s[1][0], s[1][1]), fmaxf(s[1][2], s[1][3])));
        mt = fmaxf(mt, fmaxf(fmaxf(fmaxf(s[2][0], s[2][1]), fmaxf(s[2][2], s[2][3])),
                             fmaxf(fmaxf(s[3][0], s[3][1]), fmaxf(s[3][2], s[3][3]))));
        mt = fmaxf(mt, __shfl_xor(mt, 16));
        mt = fmaxf(mt, __shfl_xor(mt, 32));
        const float mnew = fmaxf(mrow, mt);
        const float f = exp2f((mrow - mnew) * C1);
        mrow = mnew;
        const float nb = mnew * C1;
        float p[4][4];
        float sum = 0.f;
#pragma unroll
        for (int t = 0; t < 4; ++t) {
            float st = 0.f;
#pragma unroll
            for (int j = 0; j < 4; ++j) {
                p[t][j] = exp2f(fmaf(s[t][j], C1, -nb));
                st += p[t][j];
            }
            sum += st;
        }
        sum += __shfl_xor(sum, 16);
        sum += __shfl_xor(sum, 32);
        lrow = lrow * f + sum;
#pragma unroll
        for (int t = 0; t < 4; ++t)
#pragma unroll
            for (int j = 0; j < 4; ++j) oacc[t][j] *= f;
        // --- pack P to bf16 words: pw[t][r] = keys (16t+4lhi+2r, +1)
        unsigned pw[4][2];
#pragma unroll
        for (int t = 0; t < 4; ++t) {
            pw[t][0] = pack2(p[t][0], p[t][1]);
            pw[t][1] = pack2(p[t][2], p[t][3]);
        }
        // --- PV: redistribute P into B-frag, A = V^T from LDS
        const int srcA = lr + ((lane & 16) << 1);   // lr + 32*(lhi&1)
        const int srcB = srcA + 16;
        const bool hi2 = lane >= 32;                 // lhi>>1
#pragma unroll
        for (int ks = 0; ks < 2; ++ks) {
            const unsigned a0 = __shfl(pw[2 * ks][0], srcA), b0 = __shfl(pw[2 * ks + 1][0], srcA);
            const unsigned a1 = __shfl(pw[2 * ks][1], srcA), b1 = __shfl(pw[2 * ks + 1][1], srcA);
            const unsigned a2 = __shfl(pw[2 * ks][0], srcB), b2 = __shfl(pw[2 * ks + 1][0], srcB);
            const unsigned a3 = __shfl(pw[2 * ks][1], srcB), b3 = __shfl(pw[2 * ks + 1][1], srcB);
            uint4 bw;
            bw.x = hi2 ? b0 : a0; bw.y = hi2 ? b1 : a1;
            bw.z = hi2 ? b2 : a2; bw.w = hi2 ? b3 : a3;
            const bf16x8 pf = __builtin_bit_cast(bf16x8, bw);
            __builtin_amdgcn_s_setprio(1);
#pragma unroll
            for (int t = 0; t < 4; ++t) {
                const int rd = t * 16 + lr;
                const bf16x8 vf = *(const bf16x8*)((const char*)&Vt[cur][0] + rd * 128 + ((ks * 64 + lhi * 16) ^ ((rd & 7) << 4)));
                oacc[t] = __builtin_amdgcn_mfma_f32_16x16x32_bf16(vf, pf, oacc[t], 0, 0, 0);
            }
            __builtin_amdgcn_s_setprio(0);
        }
        if (more) {
            vtrans(vA, vB, cur ^ 1);
            __syncthreads();
        }
    }
    // --- epilogue: O[d][q=lr] per lane, d = 16t+4lhi+j contiguous in j
    const float inv = 1.f / lrow;
    const size_t base = (size_t)(b * Tn + q0 + w * 16 + lr) * 512 + h * 64;
#pragma unroll
    for (int t = 0; t < 4; ++t) {
        ushort4 st = make_ushort4(f2b(oacc[t][0] * inv), f2b(oacc[t][1] * inv),
                                  f2b(oacc[t][2] * inv), f2b(oacc[t][3] * inv));
        *(ushort4*)&out[base + t * 16 + lhi * 4] = st;
    }
}

// ---------------------------------------------------------------------------
// LayerNorm, one wave per row; PE variant writes fp32, layer variant bf16
// ---------------------------------------------------------------------------
__device__ __forceinline__ float pe_val(int t, int d) {
    const int k = d & ~1;
    const float invf = __expf(-(float)k * (9.210340371976184f / 512.f));
    const float ang = (float)t * invf;
    return (d & 1) ? cosf(ang) : sinf(ang);
}

template<bool OB, bool PE>
__global__ __launch_bounds__(256)
void ln_k(const float* __restrict__ in, float* __restrict__ outf, u16* __restrict__ outb,
          const float* __restrict__ g, const float* __restrict__ bsh)
{
    const int lane = threadIdx.x & 63;
    const int row = blockIdx.x * 4 + (threadIdx.x >> 6);
    const float* src = in + (size_t)row * Dm;
    const int c0 = lane * 4;
    const float4 v0 = *(const float4*)(src + c0);
    const float4 v1 = *(const float4*)(src + 256 + c0);
    float s  = v0.x + v0.y + v0.z + v0.w + v1.x + v1.y + v1.z + v1.w;
    float ss = v0.x * v0.x + v0.y * v0.y + v0.z * v0.z + v0.w * v0.w
             + v1.x * v1.x + v1.y * v1.y + v1.z * v1.z + v1.w * v1.w;
#pragma unroll
    for (int off = 32; off; off >>= 1) { s += __shfl_xor(s, off); ss += __shfl_xor(ss, off); }
    const float mean = s * (1.f / 512.f);
    const float var = ss * (1.f / 512.f) - mean * mean;
    const float rstd = rsqrtf(var + 1e-5f);
    const float4 g0 = *(const float4*)(g + c0),   g1 = *(const float4*)(g + 256 + c0);
    const float4 b0 = *(const float4*)(bsh + c0), b1 = *(const float4*)(bsh + 256 + c0);
    float o0[4] = {(v0.x - mean) * rstd * g0.x + b0.x, (v0.y - mean) * rstd * g0.y + b0.y,
                   (v0.z - mean) * rstd * g0.z + b0.z, (v0.w - mean) * rstd * g0.w + b0.w};
    float o1[4] = {(v1.x - mean) * rstd * g1.x + b1.x, (v1.y - mean) * rstd * g1.y + b1.y,
                   (v1.z - mean) * rstd * g1.z + b1.z, (v1.w - mean) * rstd * g1.w + b1.w};
    if constexpr (PE) {
        const int t = row & (Tn - 1);
#pragma unroll
        for (int j = 0; j < 4; ++j) { o0[j] += pe_val(t, c0 + j); o1[j] += pe_val(t, 256 + c0 + j); }
    }
    if constexpr (OB) {
        *(ushort4*)(outb + (size_t)row * Dm + c0) =
            make_ushort4(f2b(o0[0]), f2b(o0[1]), f2b(o0[2]), f2b(o0[3]));
        *(ushort4*)(outb + (size_t)row * Dm + 256 + c0) =
            make_ushort4(f2b(o1[0]), f2b(o1[1]), f2b(o1[2]), f2b(o1[3]));
    } else {
        *(float4*)(outf + (size_t)row * Dm + c0) = make_float4(o0[0], o0[1], o0[2], o0[3]);
        *(float4*)(outf + (size_t)row * Dm + 256 + c0) = make_float4(o1[0], o1[1], o1[2], o1[3]);
    }
}

// ---------------------------------------------------------------------------
// helpers
// ---------------------------------------------------------------------------
__global__ void cvt_layer_k(const float* __restrict__ inw, const float* __restrict__ outw,
                            const float* __restrict__ ff1w, const float* __restrict__ ff2w,
                            int layer, u16* __restrict__ dst) {
    const int i = (blockIdx.x * 256 + threadIdx.x) * 8;
    const float* src;
    if (i < 786432)       src = inw  + (size_t)layer *  786432 + i;
    else if (i < 1048576) src = outw + (size_t)layer *  262144 + (i - 786432);
    else if (i < 2097152) src = ff1w + (size_t)layer * 1048576 + (i - 1048576);
    else                  src = ff2w + (size_t)layer * 1048576 + (i - 2097152);
    const float4 a = *(const float4*)src, b = *(const float4*)(src + 4);
    uint4 o; o.x = pack2(a.x, a.y); o.y = pack2(a.z, a.w); o.z = pack2(b.x, b.y); o.w = pack2(b.z, b.w);
    *(uint4*)(dst + i) = o;
}
__global__ void cvt8_k(const float* __restrict__ in, u16* __restrict__ out, int n8) {
    const int t = blockIdx.x * 256 + threadIdx.x;
    if (t >= n8) return;
    const int i = t * 8;
    const float4 a = *(const float4*)(in + i), b = *(const float4*)(in + i + 4);
    uint4 o; o.x = pack2(a.x, a.y); o.y = pack2(a.z, a.w); o.z = pack2(b.x, b.y); o.w = pack2(b.z, b.w);
    *(uint4*)(out + i) = o;
}
__global__ void padposes_k(const float* __restrict__ p, u16* __restrict__ o, int rows) {
    const int i = blockIdx.x * 256 + threadIdx.x;
    if (i >= rows * 256) return;
    const int r = i >> 8, c = i & 255;
    o[i] = (c < INDIM) ? f2b(p[r * INDIM + c]) : (u16)0;
}
__global__ void zero_k(uint4* __restrict__ p, int n16) {
    const int i = blockIdx.x * 256 + threadIdx.x;
    if (i < n16) p[i] = make_uint4(0, 0, 0, 0);
}
__global__ void pool_k(const float* __restrict__ x, u16* __restrict__ o) {
    const int i = blockIdx.x * 256 + threadIdx.x;
    if (i >= 262144) return;
    const int flat = i * 4;
    const int row = flat >> 9, col = flat & 511;
    const int b = row >> 9, t2 = row & 511;
    const float* p0 = x + ((size_t)(b * Tn + 2 * t2) << 9) + col;
    const float4 u = *(const float4*)p0;
    const float4 w = *(const float4*)(p0 + 512);
    ushort4 r = make_ushort4(f2b(0.5f * (u.x + w.x)), f2b(0.5f * (u.y + w.y)),
                             f2b(0.5f * (u.z + w.z)), f2b(0.5f * (u.w + w.w)));
    *(ushort4*)(o + (((size_t)(b * 516 + 2 + t2)) << 9) + col) = r;
}
__global__ void wtrans_k(const float* __restrict__ w, u16* __restrict__ wt, int KS) {
    const int i = blockIdx.x * 256 + threadIdx.x;
    if (i >= 512 * 512 * KS) return;
    const int o = i / (512 * KS);
    const int rem = i - o * (512 * KS);
    const int c = rem / KS, ks = rem - c * KS;
    wt[((size_t)o * KS + ks) * 512 + c] = f2b(w[i]);
}
__global__ void bnfold_k(const float* __restrict__ g, const float* __restrict__ b,
                         const float* __restrict__ m, const float* __restrict__ v,
                         const float* __restrict__ cb, float* __restrict__ sc, float* __restrict__ sh) {
    const int i = blockIdx.x * blockDim.x + threadIdx.x;
    if (i < Dm) {
        const float s = g[i] * rsqrtf(v[i] + 1e-5f);
        sc[i] = s;
        sh[i] = (cb[i] - m[i]) * s + b[i];
    }
}

// ---------------------------------------------------------------------------
extern "C" void kernel_launch(void* const* d_in, const int* in_sizes, int n_in,
                              void* d_out, int out_size, void* d_ws, size_t ws_size,
                              hipStream_t stream)
{
    (void)in_sizes; (void)n_in; (void)out_size; (void)ws_size;
    const float* poses   = (const float*)d_in[0];
    const float* embed_w = (const float*)d_in[1];
    const float* embed_b = (const float*)d_in[2];
    const float* ln0_g   = (const float*)d_in[3];
    const float* ln0_b   = (const float*)d_in[4];
    const float* inw  = (const float*)d_in[5];
    const float* inb  = (const float*)d_in[6];
    const float* outw = (const float*)d_in[7];
    const float* outb = (const float*)d_in[8];
    const float* ln1g = (const float*)d_in[9];
    const float* ln1b = (const float*)d_in[10];
    const float* ln2g = (const float*)d_in[11];
    const float* ln2b = (const float*)d_in[12];
    const float* ff1w = (const float*)d_in[13];
    const float* ff1b = (const float*)d_in[14];
    const float* ff2w = (const float*)d_in[15];
    const float* ff2b = (const float*)d_in[16];
    const float* conv1w = (const float*)d_in[17];
    const float* conv1b = (const float*)d_in[18];
    const float* bn1g = (const float*)d_in[19];
    const float* bn1b = (const float*)d_in[20];
    const float* bn1m = (const float*)d_in[21];
    const float* bn1v = (const float*)d_in[22];
    const float* conv2w = (const float*)d_in[23];
    const float* conv2b = (const float*)d_in[24];
    const float* bn2g = (const float*)d_in[25];
    const float* bn2b = (const float*)d_in[26];
    const float* bn2m = (const float*)d_in[27];
    const float* bn2v = (const float*)d_in[28];
    const float* fc1w = (const float*)d_in[29];
    const float* fc1b = (const float*)d_in[30];
    const float* fc2w = (const float*)d_in[31];
    const float* fc2b = (const float*)d_in[32];

    char* ws = (char*)d_ws;
    float* x    = (float*)(ws);                       // 8MB fp32 residual stream
    float* resb = (float*)(ws + (8u << 20));          // 8MB
    char* big   = ws + (16u << 20);                   // 24MB: qkv16 / embed out / tail
    u16* qkv16  = (u16*)big;                          // [4096][1536] bf16 = 12MB
    u16* hb16   = (u16*)(ws + (40u << 20));           // 4MB (LN out; also poses pad)
    u16* ctx16  = (u16*)(ws + (44u << 20));           // 4MB
    u16* ff116  = (u16*)(ws + (48u << 20));           // 16MB
    u16* wbuf   = (u16*)(ws + (64u << 20));           // 6.3MB per-layer weights
    float* outp = (float*)d_out;

    // tail buffers inside big
    char* tb = big;
    u16* poolpad = (u16*)tb;                          // [4][516][512]
    u16* c1pad   = (u16*)(tb + 2113536);              // [4][514][512]
    u16* c2o16   = (u16*)(tb + 4218880);              // [2048][512]
    u16* f1o16   = (u16*)(tb + 6316032);              // [2048][256]
    u16* w1t16   = (u16*)(tb + 7364608);              // [512][2560]
    u16* w2t16   = (u16*)(tb + 9986048);              // [512][1536]
    u16* fc1w16  = (u16*)(tb + 11558912);             // [256][512]
    u16* fc2w16  = (u16*)(tb + 11821056);             // [1296][256]
    float* sc1   = (float*)(tb + 12484608);
    float* sh1   = sc1 + 512;
    float* sc2   = sh1 + 512;
    float* sh2   = sc2 + 512;
    u16* embw16  = (u16*)(tb + (20u << 20));          // [512][256]
    float* embout = (float*)(tb + (16u << 20));       // [4096][512] fp32
    u16* pospad  = hb16;                              // [4096][256]

    const u16* wq  = wbuf;
    const u16* wo  = wbuf + 786432;
    const u16* wf1 = wbuf + 1048576;
    const u16* wf2 = wbuf + 2097152;

    // ---- head ----
    padposes_k<<<4096, 256, 0, stream>>>(poses, pospad, 4096);
    padposes_k<<<512, 256, 0, stream>>>(embed_w, embw16, 512);
    gemm_bf<EPI_BIAS, false, 0, 0, 64, 0><<<dim3(4, 64), 256, 0, stream>>>(
        pospad, 256, embw16, embout, nullptr, Mseq, 512, 256, embed_b, nullptr, nullptr, nullptr, nullptr, nullptr);
    ln_k<false, true><<<1024, 256, 0, stream>>>(embout, x, nullptr, ln0_g, ln0_b);

    // ---- transformer layers ----
    for (int i = 0; i < 8; ++i) {
        cvt_layer_k<<<1536, 256, 0, stream>>>(inw, outw, ff1w, ff2w, i, wbuf);
        ln_k<true, false><<<1024, 256, 0, stream>>>(x, nullptr, hb16, ln1g + i * 512, ln1b + i * 512);
        gemm_bf<EPI_BIAS, true, 0, 0, 128, 0><<<dim3(12, 32), 256, 0, stream>>>(
            hb16, 512, wq, nullptr, qkv16, Mseq, 1536, 512, inb + i * 1536, nullptr, nullptr, nullptr, nullptr, nullptr);
        attn_mfma<<<dim3(512), 256, 0, stream>>>(qkv16, ctx16);
        gemm_bf<EPI_BIAS_RES, false, 0, 0, 64, 0><<<dim3(4, 64), 256, 0, stream>>>(
            ctx16, 512, wo, x, nullptr, Mseq, 512, 512, outb + i * 512, x, nullptr, nullptr, nullptr, nullptr);
        ln_k<true, false><<<1024, 256, 0, stream>>>(x, nullptr, hb16, ln2g + i * 512, ln2b + i * 512);
        gemm_bf<EPI_BIAS_RELU, true, 0, 0, 128, 0><<<dim3(16, 32), 256, 0, stream>>>(
            hb16, 512, wf1, nullptr, ff116, Mseq, 2048, 512, ff1b + i * 2048, nullptr, nullptr, nullptr, nullptr, nullptr);
        // FF2 with fused inter-block residual handling:
        //   i==1: save x->resb; i==3,5: add resb & save; i==7: add resb
        if (i == 1)
            gemm_bf<EPI_BIAS_RES, false, 0, 0, 64, 2><<<dim3(4, 64), 256, 0, stream>>>(
                ff116, 2048, wf2, x, nullptr, Mseq, 512, 2048, ff2b + i * 512, x, nullptr, nullptr, nullptr, resb);
        else if (i == 3 || i == 5)
            gemm_bf<EPI_BIAS_RES, false, 0, 0, 64, 3><<<dim3(4, 64), 256, 0, stream>>>(
                ff116, 2048, wf2, x, nullptr, Mseq, 512, 2048, ff2b + i * 512, x, nullptr, nullptr, resb, resb);
        else if (i == 7)
            gemm_bf<EPI_BIAS_RES, false, 0, 0, 64, 1><<<dim3(4, 64), 256, 0, stream>>>(
                ff116, 2048, wf2, x, nullptr, Mseq, 512, 2048, ff2b + i * 512, x, nullptr, nullptr, resb, nullptr);
        else
            gemm_bf<EPI_BIAS_RES, false, 0, 0, 64, 0><<<dim3(4, 64), 256, 0, stream>>>(
                ff116, 2048, wf2, x, nullptr, Mseq, 512, 2048, ff2b + i * 512, x, nullptr, nullptr, nullptr, nullptr);
    }

    // ---- tail ----
    zero_k<<<516, 256, 0, stream>>>((uint4*)poolpad, 132096);
    pool_k<<<1024, 256, 0, stream>>>(x, poolpad);
    wtrans_k<<<5120, 256, 0, stream>>>(conv1w, w1t16, 5);
    bnfold_k<<<2, 256, 0, stream>>>(bn1g, bn1b, bn1m, bn1v, conv1b, sc1, sh1);
    zero_k<<<514, 256, 0, stream>>>((uint4*)c1pad, 131584);
    gemm_bf<EPI_SS_GELU, true, 2, 1, 64, 0><<<dim3(4, 32), 256, 0, stream>>>(
        poolpad, 512, w1t16, nullptr, c1pad, Mtc, 512, 2560, nullptr, nullptr, sc1, sh1, nullptr, nullptr);
    wtrans_k<<<3072, 256, 0, stream>>>(conv2w, w2t16, 3);
    bnfold_k<<<2, 256, 0, stream>>>(bn2g, bn2b, bn2m, bn2v, conv2b, sc2, sh2);
    gemm_bf<EPI_SS_GELU, true, 1, 0, 64, 0><<<dim3(4, 32), 256, 0, stream>>>(
        c1pad, 512, w2t16, nullptr, c2o16, Mtc, 512, 1536, nullptr, nullptr, sc2, sh2, nullptr, nullptr);
    cvt8_k<<<64, 256, 0, stream>>>(fc1w, fc1w16, 16384);
    cvt8_k<<<162, 256, 0, stream>>>(fc2w, fc2w16, 41472);
    gemm_bf<EPI_BIAS_GELU, true, 0, 0, 64, 0><<<dim3(2, 32), 256, 0, stream>>>(
        c2o16, 512, fc1w16, nullptr, f1o16, Mtc, 256, 512, fc1b, nullptr, nullptr, nullptr, nullptr, nullptr);
    gemm_bf<EPI_BIAS, false, 0, 0, 64, 0><<<dim3(11, 32), 256, 0, stream>>>(
        f1o16, 256, fc2w16, outp, nullptr, Mtc, 1296, 256, fc2b, nullptr, nullptr, nullptr, nullptr, nullptr);
}